// Round 1
// baseline (831.345 us; speedup 1.0000x reference)
//
#include <hip/hip_runtime.h>
#include <hip/hip_bf16.h>
#include <math.h>

typedef float f32x4 __attribute__((ext_vector_type(4)));
typedef short s16x8 __attribute__((ext_vector_type(8)));
typedef __bf16 bf16x8 __attribute__((ext_vector_type(8)));

__device__ __forceinline__ unsigned short f2bf(float f) {
  unsigned int u = __builtin_bit_cast(unsigned int, f);
  u += 0x7fffu + ((u >> 16) & 1u);
  return (unsigned short)(u >> 16);
}

__device__ __forceinline__ f32x4 mfma16(s16x8 a, s16x8 b, f32x4 c) {
  return __builtin_amdgcn_mfma_f32_16x16x32_bf16(
      __builtin_bit_cast(bf16x8, a), __builtin_bit_cast(bf16x8, b), c, 0, 0, 0);
}

#define GLDS(gp, lp) __builtin_amdgcn_global_load_lds(                      \
    (__attribute__((address_space(1))) void*)(gp),                          \
    (__attribute__((address_space(3))) void*)(lp), 16, 0, 0)

struct __attribute__((aligned(8))) us4 { unsigned short x, y, z, w; };
__device__ __forceinline__ us4 cvt4(float4 v) {
  us4 r; r.x = f2bf(v.x); r.y = f2bf(v.y); r.z = f2bf(v.z); r.w = f2bf(v.w);
  return r;
}

// ---------------------------------------------------------------- convert all
__global__ __launch_bounds__(256) void conv_all(
    const float4* __restrict__ h, const float4* __restrict__ wq,
    const float4* __restrict__ wk, const float4* __restrict__ wv,
    const float4* __restrict__ wo, const float4* __restrict__ bq,
    const float4* __restrict__ bk, const float4* __restrict__ bv,
    us4* __restrict__ hbf, us4* __restrict__ wqkvbf, us4* __restrict__ wobf,
    float4* __restrict__ biasc)
{
  const unsigned int U = 20973056u;
  const unsigned int stride = gridDim.x * blockDim.x;
  for (unsigned int u = blockIdx.x * blockDim.x + threadIdx.x; u < U; u += stride) {
    if (u < 4194304u) {
      hbf[u] = cvt4(h[u]);
    } else if (u < 12582912u) {
      unsigned int o = u - 4194304u;  wqkvbf[o] = cvt4(wq[o]);
    } else if (u < 14680064u) {
      unsigned int o = u - 12582912u; wqkvbf[8388608u + o] = cvt4(wk[o]);
    } else if (u < 16777216u) {
      unsigned int o = u - 14680064u; wqkvbf[10485760u + o] = cvt4(wv[o]);
    } else if (u < 20971520u) {
      unsigned int o = u - 16777216u; wobf[o] = cvt4(wo[o]);
    } else {
      unsigned int o = u - 20971520u;
      float4 v = (o < 1024u) ? bq[o] : (o < 1280u) ? bk[o - 1024u] : bv[o - 1280u];
      biasc[o] = v;
    }
  }
}

// ---------------------------------------------------------------- rope table
__global__ __launch_bounds__(256) void rope_table(const int* __restrict__ pos_ids,
                                                  float* __restrict__ cost,
                                                  float* __restrict__ sint)
{
  int idx = blockIdx.x * blockDim.x + threadIdx.x;
  if (idx >= 131072) return;
  int s = idx >> 6, i = idx & 63;
  double invf = exp(-((double)i / 64.0) * 9.210340371976184);  // ln(10000)
  double ang = (double)pos_ids[s] * invf;
  cost[idx] = (float)cos(ang);
  sint[idx] = (float)sin(ang);
}

// ---------------------------------------------------------------- GEMM (C = A * B^T + bias)
// A: M x K bf16 row-major, B: N x K bf16 row-major, C: M x N fp32.
// m97 structure: 128x128 tile, BK=32, 4 waves, 16 mfma/wave/K-step.
__global__ __launch_bounds__(256) void gemm_bt(const unsigned short* __restrict__ A,
                                               const unsigned short* __restrict__ B,
                                               const float* __restrict__ bias,
                                               float* __restrict__ C,
                                               int M, int N, int K)
{
  __shared__ char lds[16384];
  char* As = lds;
  char* Bs = lds + 8192;
  const int tid = threadIdx.x;
  const int l = tid & 63;
  const int w = tid >> 6;
  const int wr = (w >> 1) * 64, wc = (w & 1) * 64;
  const size_t arow0 = (size_t)blockIdx.y * 128;
  const size_t brow0 = (size_t)blockIdx.x * 128;
  const char* Ab = (const char*)A;
  const char* Bb = (const char*)B;

  f32x4 acc[4][4];
#pragma unroll
  for (int i = 0; i < 4; ++i)
#pragma unroll
    for (int j = 0; j < 4; ++j) acc[i][j] = (f32x4){0.f, 0.f, 0.f, 0.f};

  const int rb = (l & 15);
  const int kb = (l >> 4) * 16;

  for (int k0 = 0; k0 < K; k0 += 32) {
#pragma unroll
    for (int j = 0; j < 2; ++j) {
      const int flat = (j * 256 + tid) * 16;
      const int row = flat >> 6;
      const int colb = flat & 63;
      const size_t ga = ((arow0 + row) * (size_t)K + k0) * 2 + colb;
      const size_t gb = ((brow0 + row) * (size_t)K + k0) * 2 + colb;
      GLDS(Ab + ga, As + (j * 256 + (tid & 192)) * 16);
      GLDS(Bb + gb, Bs + (j * 256 + (tid & 192)) * 16);
    }
    __syncthreads();
    s16x8 a[4], b[4];
#pragma unroll
    for (int i = 0; i < 4; ++i) {
      a[i] = *(const s16x8*)(As + (wr + i * 16 + rb) * 64 + kb);
      b[i] = *(const s16x8*)(Bs + (wc + i * 16 + rb) * 64 + kb);
    }
#pragma unroll
    for (int mi = 0; mi < 4; ++mi)
#pragma unroll
      for (int ni = 0; ni < 4; ++ni)
        acc[mi][ni] = mfma16(a[mi], b[ni], acc[mi][ni]);
    __syncthreads();
  }

  const int r0 = (int)arow0 + wr + (l >> 4) * 4;
  const int c0 = (int)brow0 + wc + (l & 15);
#pragma unroll
  for (int mi = 0; mi < 4; ++mi) {
#pragma unroll
    for (int ni = 0; ni < 4; ++ni) {
      const int c = c0 + ni * 16;
      const float bvv = bias ? bias[c] : 0.f;
#pragma unroll
      for (int rr = 0; rr < 4; ++rr) {
        const int r = r0 + mi * 16 + rr;
        C[(size_t)r * N + c] = acc[mi][ni][rr] + bvv;
      }
    }
  }
}

// ---------------------------------------------------------------- RoPE + scatter
// Reads qkv fp32 (2048 x 6144 = [Q 4096 | K 1024 | V 1024]).
// Writes: qbf (32,2048,128) bf16 with 1/sqrt(128) folded;
//         key/value outputs fp32 (8,4096,128) incl. cache copy;
//         kswz: per (kh, tile t of 64 rows) 16KB swizzled [64][128] bf16, byte ^= (row&7)<<4
//         vswz: per (kh, t) 16KB swizzled V^T [128][64] bf16, byte ^= (d&7)<<4
__global__ __launch_bounds__(256) void rope_scatter(
    const float* __restrict__ qkv, const float* __restrict__ cost,
    const float* __restrict__ sint, const float* __restrict__ cache_k,
    const float* __restrict__ cache_v, float* __restrict__ keyout,
    float* __restrict__ valout, unsigned short* __restrict__ qbf,
    char* __restrict__ kswz, char* __restrict__ vswz)
{
  const float rs = 0.08838834764831845f;  // 1/sqrt(128)
  const int stride = gridDim.x * blockDim.x;
  for (int idx = blockIdx.x * blockDim.x + threadIdx.x; idx < 11534336; idx += stride) {
    if (idx < 4194304) {                       // Q rope
      int i = idx & 63, hh = (idx >> 6) & 31, s = idx >> 11;
      const float* base = qkv + (size_t)s * 6144 + hh * 128 + i;
      float q1 = base[0], q2 = base[64];
      float c = cost[s * 64 + i], sn = sint[s * 64 + i];
      float o1 = (q1 * c - q2 * sn) * rs, o2 = (q2 * c + q1 * sn) * rs;
      unsigned short* qd = qbf + ((size_t)hh * 2048 + s) * 128 + i;
      qd[0] = f2bf(o1); qd[64] = f2bf(o2);
    } else if (idx < 5242880) {                // K rope + outputs
      int j = idx - 4194304;
      int i = j & 63, kh = (j >> 6) & 7, s = j >> 9;
      const float* base = qkv + (size_t)s * 6144 + 4096 + kh * 128 + i;
      float k1 = base[0], k2 = base[64];
      float c = cost[s * 64 + i], sn = sint[s * 64 + i];
      float o1 = k1 * c - k2 * sn, o2 = k2 * c + k1 * sn;
      float* kd = keyout + ((size_t)kh * 4096 + 2048 + s) * 128 + i;
      kd[0] = o1; kd[64] = o2;
      int t = 32 + (s >> 6), r = s & 63;
      char* tb = kswz + (size_t)(kh * 64 + t) * 16384;
      *(unsigned short*)(tb + ((r * 256 + i * 2) ^ ((r & 7) << 4))) = f2bf(o1);
      *(unsigned short*)(tb + ((r * 256 + (i + 64) * 2) ^ ((r & 7) << 4))) = f2bf(o2);
    } else if (idx < 7340032) {                // V new
      int j = idx - 5242880;
      int d = j & 127, kh = (j >> 7) & 7, s = j >> 10;
      float v = qkv[(size_t)s * 6144 + 5120 + kh * 128 + d];
      valout[((size_t)kh * 4096 + 2048 + s) * 128 + d] = v;
      int t = 32 + (s >> 6), c = s & 63;
      char* tb = vswz + (size_t)(kh * 64 + t) * 16384;
      *(unsigned short*)(tb + ((d * 128 + c * 2) ^ ((d & 7) << 4))) = f2bf(v);
    } else if (idx < 9437184) {                // cache K copy
      int j = idx - 7340032;
      int d = j & 127, s = (j >> 7) & 2047, kh = j >> 18;
      float v = cache_k[(size_t)(kh * 2048 + s) * 128 + d];
      keyout[((size_t)kh * 4096 + s) * 128 + d] = v;
      int t = s >> 6, r = s & 63;
      char* tb = kswz + (size_t)(kh * 64 + t) * 16384;
      *(unsigned short*)(tb + ((r * 256 + d * 2) ^ ((r & 7) << 4))) = f2bf(v);
    } else {                                   // cache V copy
      int j = idx - 9437184;
      int d = j & 127, s = (j >> 7) & 2047, kh = j >> 18;
      float v = cache_v[(size_t)(kh * 2048 + s) * 128 + d];
      valout[((size_t)kh * 4096 + s) * 128 + d] = v;
      int t = s >> 6, c = s & 63;
      char* tb = vswz + (size_t)(kh * 64 + t) * 16384;
      *(unsigned short*)(tb + ((d * 128 + c * 2) ^ ((d & 7) << 4))) = f2bf(v);
    }
  }
}

// ---------------------------------------------------------------- flash attention
// grid (32 q-tiles, 32 heads), 4 waves/block, wave owns 16 q-rows, KVBLK=64.
__global__ __launch_bounds__(256) void attn_fwd(const unsigned short* __restrict__ qbf,
                                                const char* __restrict__ kswz,
                                                const char* __restrict__ vswz,
                                                unsigned short* __restrict__ ctx)
{
  __shared__ char smem[40960];  // Kt 16K | Vt 16K | P 4x2K
  char* Kt = smem;
  char* Vt = smem + 16384;
  char* Ps = smem + 32768;
  const int tid = threadIdx.x;
  const int l = tid & 63;
  const int w = tid >> 6;
  const int qt = blockIdx.x;
  const int h = blockIdx.y;
  const int kh = h >> 2;
  const int nt = qt + 33;
  const int qrow16 = (l >> 4) * 4;

  s16x8 aq[4];
  {
    const int qr = qt * 64 + w * 16 + (l & 15);
    const unsigned short* qp = qbf + ((size_t)h * 2048 + qr) * 128 + (l >> 4) * 8;
#pragma unroll
    for (int kc = 0; kc < 4; ++kc) aq[kc] = *(const s16x8*)(qp + kc * 32);
  }
  f32x4 o[8];
#pragma unroll
  for (int i = 0; i < 8; ++i) o[i] = (f32x4){0.f, 0.f, 0.f, 0.f};
  float m[4] = {-1e30f, -1e30f, -1e30f, -1e30f};
  float ls[4] = {0.f, 0.f, 0.f, 0.f};

  const char* kb0 = kswz + (size_t)kh * 64 * 16384;
  const char* vb0 = vswz + (size_t)kh * 64 * 16384;
  char* Pw = Ps + w * 2048;

  for (int t = 0; t < nt; ++t) {
    const char* kb = kb0 + (size_t)t * 16384;
    const char* vb = vb0 + (size_t)t * 16384;
#pragma unroll
    for (int j = 0; j < 4; ++j) {
      GLDS(kb + ((j * 4 + w) * 64 + l) * 16, Kt + (j * 4 + w) * 1024);
      GLDS(vb + ((j * 4 + w) * 64 + l) * 16, Vt + (j * 4 + w) * 1024);
    }
    __syncthreads();

    // QK^T: S (16 q x 64 kv)
    f32x4 s[4];
#pragma unroll
    for (int i = 0; i < 4; ++i) s[i] = (f32x4){0.f, 0.f, 0.f, 0.f};
#pragma unroll
    for (int kc = 0; kc < 4; ++kc) {
      const int d0b = (kc * 32 + (l >> 4) * 8) * 2;
#pragma unroll
      for (int ni = 0; ni < 4; ++ni) {
        const int row = ni * 16 + (l & 15);
        s16x8 kf = *(const s16x8*)(Kt + ((row * 256 + d0b) ^ ((row & 7) << 4)));
        s[ni] = mfma16(aq[kc], kf, s[ni]);
      }
    }
    if (t == nt - 1) {  // diagonal chunk: causal mask
      const int qpos_b = 2048 + qt * 64 + w * 16 + qrow16;
      const int kvcol = (l & 15);
#pragma unroll
      for (int ni = 0; ni < 4; ++ni) {
        const int kvpos = t * 64 + ni * 16 + kvcol;
#pragma unroll
        for (int rr = 0; rr < 4; ++rr)
          if (kvpos > qpos_b + rr) s[ni][rr] = -1e30f;
      }
    }
    // online softmax (rows live in lane groups of 16; reduce over lane bits 0-3)
    float rm[4];
#pragma unroll
    for (int rr = 0; rr < 4; ++rr)
      rm[rr] = fmaxf(fmaxf(s[0][rr], s[1][rr]), fmaxf(s[2][rr], s[3][rr]));
#pragma unroll
    for (int rr = 0; rr < 4; ++rr) {
      float v = rm[rr];
      v = fmaxf(v, __shfl_xor(v, 1));
      v = fmaxf(v, __shfl_xor(v, 2));
      v = fmaxf(v, __shfl_xor(v, 4));
      v = fmaxf(v, __shfl_xor(v, 8));
      rm[rr] = v;
    }
    float fs[4];
#pragma unroll
    for (int rr = 0; rr < 4; ++rr) {
      const float nm = fmaxf(m[rr], rm[rr]);
      fs[rr] = __expf(m[rr] - nm);
      m[rr] = nm;
    }
#pragma unroll
    for (int i = 0; i < 8; ++i)
#pragma unroll
      for (int rr = 0; rr < 4; ++rr) o[i][rr] *= fs[rr];
    float rsum[4] = {0.f, 0.f, 0.f, 0.f};
#pragma unroll
    for (int ni = 0; ni < 4; ++ni)
#pragma unroll
      for (int rr = 0; rr < 4; ++rr) {
        const float p = __expf(s[ni][rr] - m[rr]);
        s[ni][rr] = p;
        rsum[rr] += p;
      }
#pragma unroll
    for (int rr = 0; rr < 4; ++rr) {
      float v = rsum[rr];
      v += __shfl_xor(v, 1);
      v += __shfl_xor(v, 2);
      v += __shfl_xor(v, 4);
      v += __shfl_xor(v, 8);
      ls[rr] = ls[rr] * fs[rr] + v;
    }
    // P -> LDS (bf16, swizzled per q-row)
#pragma unroll
    for (int ni = 0; ni < 4; ++ni) {
      const int colb = (ni * 16 + (l & 15)) * 2;
#pragma unroll
      for (int rr = 0; rr < 4; ++rr) {
        const int q = qrow16 + rr;
        *(unsigned short*)(Pw + ((q * 128 + colb) ^ ((q & 7) << 4))) = f2bf(s[ni][rr]);
      }
    }
    // PV: ctx += P (16x64) * V (64x128)
    s16x8 pa[2];
#pragma unroll
    for (int kc2 = 0; kc2 < 2; ++kc2) {
      const int q = l & 15;
      const int kvb = (kc2 * 32 + (l >> 4) * 8) * 2;
      pa[kc2] = *(const s16x8*)(Pw + ((q * 128 + kvb) ^ ((q & 7) << 4)));
    }
#pragma unroll
    for (int sub = 0; sub < 8; ++sub) {
      const int d = sub * 16 + (l & 15);
#pragma unroll
      for (int kc2 = 0; kc2 < 2; ++kc2) {
        const int kvb = (kc2 * 32 + (l >> 4) * 8) * 2;
        s16x8 vf = *(const s16x8*)(Vt + ((d * 128 + kvb) ^ ((d & 7) << 4)));
        o[sub] = mfma16(pa[kc2], vf, o[sub]);
      }
    }
    __syncthreads();
  }

  const int r0 = qt * 64 + w * 16 + qrow16;
  const int c0 = h * 128 + (l & 15);
#pragma unroll
  for (int sub = 0; sub < 8; ++sub)
#pragma unroll
    for (int rr = 0; rr < 4; ++rr) {
      const float v = o[sub][rr] / ls[rr];
      ctx[(size_t)(r0 + rr) * 4096 + c0 + sub * 16] = f2bf(v);
    }
}

// ---------------------------------------------------------------- launch
extern "C" void kernel_launch(void* const* d_in, const int* in_sizes, int n_in,
                              void* d_out, int out_size, void* d_ws, size_t ws_size,
                              hipStream_t stream) {
  (void)in_sizes; (void)n_in; (void)out_size; (void)ws_size;
  const float* hs     = (const float*)d_in[0];
  const int*   pos    = (const int*)d_in[1];
  const float* cachek = (const float*)d_in[2];
  const float* cachev = (const float*)d_in[3];
  const float* Wq     = (const float*)d_in[4];
  const float* bq     = (const float*)d_in[5];
  const float* Wk     = (const float*)d_in[6];
  const float* bk     = (const float*)d_in[7];
  const float* Wv     = (const float*)d_in[8];
  const float* bv     = (const float*)d_in[9];
  const float* Wo     = (const float*)d_in[10];

  float* out    = (float*)d_out;                     // 2048*4096
  float* keyout = out + (size_t)2048 * 4096;         // 8*4096*128
  float* valout = keyout + (size_t)8 * 4096 * 128;   // 8*4096*128

  char* ws = (char*)d_ws;
  // region A (33.5MB): hbf -> reused as {qbf, kswz, vswz} after GEMM1
  unsigned short* hbf    = (unsigned short*)(ws + 0);
  unsigned short* qbf    = (unsigned short*)(ws + 0);
  char*           kswz   = ws + 16777216;
  char*           vswz   = ws + 25165824;
  unsigned short* wqkvbf = (unsigned short*)(ws + 33554432);    // 100.7MB
  unsigned short* wobf   = (unsigned short*)(ws + 134217728);   // 33.5MB
  float*          qkvf   = (float*)(ws + 167772160);            // 50.3MB -> reused ctxbf
  unsigned short* ctxbf  = (unsigned short*)(ws + 167772160);
  float*          cost   = (float*)(ws + 218103808);
  float*          sint   = (float*)(ws + 218628096);
  float*          biasc  = (float*)(ws + 219152384);

  conv_all<<<2048, 256, 0, stream>>>((const float4*)hs, (const float4*)Wq,
                                     (const float4*)Wk, (const float4*)Wv,
                                     (const float4*)Wo, (const float4*)bq,
                                     (const float4*)bk, (const float4*)bv,
                                     (us4*)hbf, (us4*)wqkvbf, (us4*)wobf,
                                     (float4*)biasc);
  rope_table<<<512, 256, 0, stream>>>(pos, cost, sint);
  gemm_bt<<<dim3(48, 16), 256, 0, stream>>>(hbf, wqkvbf, biasc, qkvf, 2048, 6144, 8192);
  rope_scatter<<<2048, 256, 0, stream>>>(qkvf, cost, sint, cachek, cachev,
                                         keyout, valout, qbf, kswz, vswz);
  attn_fwd<<<dim3(32, 32), 256, 0, stream>>>(qbf, kswz, vswz, ctxbf);
  gemm_bt<<<dim3(32, 16), 256, 0, stream>>>(ctxbf, wobf, nullptr, out, 2048, 4096, 4096);
}

// Round 3
// 764.047 us; speedup vs baseline: 1.0881x; 1.0881x over previous
//
#include <hip/hip_runtime.h>
#include <hip/hip_bf16.h>
#include <math.h>

typedef float f32x4 __attribute__((ext_vector_type(4)));
typedef short s16x8 __attribute__((ext_vector_type(8)));
typedef __bf16 bf16x8 __attribute__((ext_vector_type(8)));

__device__ __forceinline__ unsigned short f2bf(float f) {
  unsigned int u = __builtin_bit_cast(unsigned int, f);
  u += 0x7fffu + ((u >> 16) & 1u);
  return (unsigned short)(u >> 16);
}

__device__ __forceinline__ f32x4 mfma16(s16x8 a, s16x8 b, f32x4 c) {
  return __builtin_amdgcn_mfma_f32_16x16x32_bf16(
      __builtin_bit_cast(bf16x8, a), __builtin_bit_cast(bf16x8, b), c, 0, 0, 0);
}

#define GLDS(gp, lp) __builtin_amdgcn_global_load_lds(                      \
    (__attribute__((address_space(1))) void*)(gp),                          \
    (__attribute__((address_space(3))) void*)(lp), 16, 0, 0)

struct __attribute__((aligned(8))) us4 { unsigned short x, y, z, w; };
__device__ __forceinline__ us4 cvt4(float4 v) {
  us4 r; r.x = f2bf(v.x); r.y = f2bf(v.y); r.z = f2bf(v.z); r.w = f2bf(v.w);
  return r;
}

// ---------------------------------------------------------------- convert all
__global__ __launch_bounds__(256) void conv_all(
    const float4* __restrict__ h, const float4* __restrict__ wq,
    const float4* __restrict__ wk, const float4* __restrict__ wv,
    const float4* __restrict__ wo, const float4* __restrict__ bq,
    const float4* __restrict__ bk, const float4* __restrict__ bv,
    us4* __restrict__ hbf, us4* __restrict__ wqkvbf, us4* __restrict__ wobf,
    float4* __restrict__ biasc)
{
  const unsigned int U = 20973056u;
  const unsigned int stride = gridDim.x * blockDim.x;
  for (unsigned int u = blockIdx.x * blockDim.x + threadIdx.x; u < U; u += stride) {
    if (u < 4194304u) {
      hbf[u] = cvt4(h[u]);
    } else if (u < 12582912u) {
      unsigned int o = u - 4194304u;  wqkvbf[o] = cvt4(wq[o]);
    } else if (u < 14680064u) {
      unsigned int o = u - 12582912u; wqkvbf[8388608u + o] = cvt4(wk[o]);
    } else if (u < 16777216u) {
      unsigned int o = u - 14680064u; wqkvbf[10485760u + o] = cvt4(wv[o]);
    } else if (u < 20971520u) {
      unsigned int o = u - 16777216u; wobf[o] = cvt4(wo[o]);
    } else {
      unsigned int o = u - 20971520u;
      float4 v = (o < 1024u) ? bq[o] : (o < 1280u) ? bk[o - 1024u] : bv[o - 1280u];
      biasc[o] = v;
    }
  }
}

// ---------------------------------------------------------------- rope table
__global__ __launch_bounds__(256) void rope_table(const int* __restrict__ pos_ids,
                                                  float* __restrict__ cost,
                                                  float* __restrict__ sint)
{
  int idx = blockIdx.x * blockDim.x + threadIdx.x;
  if (idx >= 131072) return;
  int s = idx >> 6, i = idx & 63;
  double invf = exp(-((double)i / 64.0) * 9.210340371976184);  // ln(10000)
  double ang = (double)pos_ids[s] * invf;
  cost[idx] = (float)cos(ang);
  sint[idx] = (float)sin(ang);
}

// ---------------------------------------------------------------- GEMM (C = A * B^T + bias)
__global__ __launch_bounds__(256) void gemm_bt(const unsigned short* __restrict__ A,
                                               const unsigned short* __restrict__ B,
                                               const float* __restrict__ bias,
                                               float* __restrict__ C,
                                               int M, int N, int K)
{
  __shared__ char lds[16384];
  char* As = lds;
  char* Bs = lds + 8192;
  const int tid = threadIdx.x;
  const int l = tid & 63;
  const int w = tid >> 6;
  const int wr = (w >> 1) * 64, wc = (w & 1) * 64;
  const size_t arow0 = (size_t)blockIdx.y * 128;
  const size_t brow0 = (size_t)blockIdx.x * 128;
  const char* Ab = (const char*)A;
  const char* Bb = (const char*)B;

  f32x4 acc[4][4];
#pragma unroll
  for (int i = 0; i < 4; ++i)
#pragma unroll
    for (int j = 0; j < 4; ++j) acc[i][j] = (f32x4){0.f, 0.f, 0.f, 0.f};

  const int rb = (l & 15);
  const int kb = (l >> 4) * 16;

  for (int k0 = 0; k0 < K; k0 += 32) {
#pragma unroll
    for (int j = 0; j < 2; ++j) {
      const int flat = (j * 256 + tid) * 16;
      const int row = flat >> 6;
      const int colb = flat & 63;
      const size_t ga = ((arow0 + row) * (size_t)K + k0) * 2 + colb;
      const size_t gb = ((brow0 + row) * (size_t)K + k0) * 2 + colb;
      GLDS(Ab + ga, As + (j * 256 + (tid & 192)) * 16);
      GLDS(Bb + gb, Bs + (j * 256 + (tid & 192)) * 16);
    }
    __syncthreads();
    s16x8 a[4], b[4];
#pragma unroll
    for (int i = 0; i < 4; ++i) {
      a[i] = *(const s16x8*)(As + (wr + i * 16 + rb) * 64 + kb);
      b[i] = *(const s16x8*)(Bs + (wc + i * 16 + rb) * 64 + kb);
    }
#pragma unroll
    for (int mi = 0; mi < 4; ++mi)
#pragma unroll
      for (int ni = 0; ni < 4; ++ni)
        acc[mi][ni] = mfma16(a[mi], b[ni], acc[mi][ni]);
    __syncthreads();
  }

  const int r0 = (int)arow0 + wr + (l >> 4) * 4;
  const int c0 = (int)brow0 + wc + (l & 15);
#pragma unroll
  for (int mi = 0; mi < 4; ++mi) {
#pragma unroll
    for (int ni = 0; ni < 4; ++ni) {
      const int c = c0 + ni * 16;
      const float bvv = bias ? bias[c] : 0.f;
#pragma unroll
      for (int rr = 0; rr < 4; ++rr) {
        const int r = r0 + mi * 16 + rr;
        C[(size_t)r * N + c] = acc[mi][ni][rr] + bvv;
      }
    }
  }
}

// ---------------------------------------------------------------- RoPE + scatter
__global__ __launch_bounds__(256) void rope_scatter(
    const float* __restrict__ qkv, const float* __restrict__ cost,
    const float* __restrict__ sint, const float* __restrict__ cache_k,
    const float* __restrict__ cache_v, float* __restrict__ keyout,
    float* __restrict__ valout, unsigned short* __restrict__ qbf,
    char* __restrict__ kswz, char* __restrict__ vswz)
{
  const float rs = 0.08838834764831845f;  // 1/sqrt(128)
  const int stride = gridDim.x * blockDim.x;
  for (int idx = blockIdx.x * blockDim.x + threadIdx.x; idx < 11534336; idx += stride) {
    if (idx < 4194304) {                       // Q rope
      int i = idx & 63, hh = (idx >> 6) & 31, s = idx >> 11;
      const float* base = qkv + (size_t)s * 6144 + hh * 128 + i;
      float q1 = base[0], q2 = base[64];
      float c = cost[s * 64 + i], sn = sint[s * 64 + i];
      float o1 = (q1 * c - q2 * sn) * rs, o2 = (q2 * c + q1 * sn) * rs;
      unsigned short* qd = qbf + ((size_t)hh * 2048 + s) * 128 + i;
      qd[0] = f2bf(o1); qd[64] = f2bf(o2);
    } else if (idx < 5242880) {                // K rope + outputs
      int j = idx - 4194304;
      int i = j & 63, kh = (j >> 6) & 7, s = j >> 9;
      const float* base = qkv + (size_t)s * 6144 + 4096 + kh * 128 + i;
      float k1 = base[0], k2 = base[64];
      float c = cost[s * 64 + i], sn = sint[s * 64 + i];
      float o1 = k1 * c - k2 * sn, o2 = k2 * c + k1 * sn;
      float* kd = keyout + ((size_t)kh * 4096 + 2048 + s) * 128 + i;
      kd[0] = o1; kd[64] = o2;
      int t = 32 + (s >> 6), r = s & 63;
      char* tb = kswz + (size_t)(kh * 64 + t) * 16384;
      *(unsigned short*)(tb + ((r * 256 + i * 2) ^ ((r & 7) << 4))) = f2bf(o1);
      *(unsigned short*)(tb + ((r * 256 + (i + 64) * 2) ^ ((r & 7) << 4))) = f2bf(o2);
    } else if (idx < 7340032) {                // V new
      int j = idx - 5242880;
      int d = j & 127, kh = (j >> 7) & 7, s = j >> 10;
      float v = qkv[(size_t)s * 6144 + 5120 + kh * 128 + d];
      valout[((size_t)kh * 4096 + 2048 + s) * 128 + d] = v;
      int t = 32 + (s >> 6), c = s & 63;
      char* tb = vswz + (size_t)(kh * 64 + t) * 16384;
      *(unsigned short*)(tb + ((d * 128 + c * 2) ^ ((d & 7) << 4))) = f2bf(v);
    } else if (idx < 9437184) {                // cache K copy
      int j = idx - 7340032;
      int d = j & 127, s = (j >> 7) & 2047, kh = j >> 18;
      float v = cache_k[(size_t)(kh * 2048 + s) * 128 + d];
      keyout[((size_t)kh * 4096 + s) * 128 + d] = v;
      int t = s >> 6, r = s & 63;
      char* tb = kswz + (size_t)(kh * 64 + t) * 16384;
      *(unsigned short*)(tb + ((r * 256 + d * 2) ^ ((r & 7) << 4))) = f2bf(v);
    } else {                                   // cache V copy
      int j = idx - 9437184;
      int d = j & 127, s = (j >> 7) & 2047, kh = j >> 18;
      float v = cache_v[(size_t)(kh * 2048 + s) * 128 + d];
      valout[((size_t)kh * 4096 + s) * 128 + d] = v;
      int t = s >> 6, c = s & 63;
      char* tb = vswz + (size_t)(kh * 64 + t) * 16384;
      *(unsigned short*)(tb + ((d * 128 + c * 2) ^ ((d & 7) << 4))) = f2bf(v);
    }
  }
}

// ---------------------------------------------------------------- flash attention
// grid 512 blocks x 512 threads (8 waves). QBLK=128, KVBLK=64.
// b = d>>5 -> qt = b<8 ? b : 23-b (pairs CU's two blocks to constant work);
// kh = d%8 (XCD-affine). Double-buffered K/V with counted vmcnt(4).
__global__ __launch_bounds__(512) void attn_fwd(const unsigned short* __restrict__ qbf,
                                                const char* __restrict__ kswz,
                                                const char* __restrict__ vswz,
                                                unsigned short* __restrict__ ctx)
{
  __shared__ char smem[81920];  // buf0: K16K|V16K; buf1: K16K|V16K; P 8x2K
  char* Ps = smem + 65536;
  const int tid = threadIdx.x;
  const int l = tid & 63;
  const int w = tid >> 6;                      // 0..7
  const int d = blockIdx.x;
  const int b = d >> 5;
  const int qt = (b < 8) ? b : 23 - b;         // 0..15, balanced pairs
  const int h = (d & 7) * 4 + ((d >> 3) & 3);  // kh = d%8
  const int kh = h >> 2;
  const int nt = 2 * qt + 34;
  const int qrow16 = (l >> 4) * 4;

  s16x8 aq[4];
  {
    const int qr = qt * 128 + w * 16 + (l & 15);
    const unsigned short* qp = qbf + ((size_t)h * 2048 + qr) * 128 + (l >> 4) * 8;
#pragma unroll
    for (int kc = 0; kc < 4; ++kc) aq[kc] = *(const s16x8*)(qp + kc * 32);
  }
  f32x4 o[8];
#pragma unroll
  for (int i = 0; i < 8; ++i) o[i] = (f32x4){0.f, 0.f, 0.f, 0.f};
  float m[4] = {-1e30f, -1e30f, -1e30f, -1e30f};
  float ls[4] = {0.f, 0.f, 0.f, 0.f};

  const char* kb0 = kswz + (size_t)kh * (64 * 16384);
  const char* vb0 = vswz + (size_t)kh * (64 * 16384);
  char* Pw = Ps + w * 2048;

  auto STAGE = [&](int t, int c) {
    const char* kb = kb0 + (size_t)t * 16384;
    const char* vb = vb0 + (size_t)t * 16384;
    char* Kt = smem + c * 32768;
    char* Vt = Kt + 16384;
#pragma unroll
    for (int j = 0; j < 2; ++j) {
      const int cw = j * 8 + w;                // 8 waves cover 16 chunks
      GLDS(kb + (cw * 64 + l) * 16, Kt + cw * 1024);
      GLDS(vb + (cw * 64 + l) * 16, Vt + cw * 1024);
    }
  };

  STAGE(0, 0);
  int c = 0;
  for (int t = 0; t < nt; ++t) {
    const int tn = (t + 1 < nt) ? t + 1 : t;
    STAGE(tn, c ^ 1);                       // 4 GLDS/wave in flight across barrier
    asm volatile("s_waitcnt vmcnt(4)" ::: "memory");  // own tile-t loads landed
    __builtin_amdgcn_s_barrier();
    asm volatile("" ::: "memory");
    const char* Kt = smem + c * 32768;
    const char* Vt = Kt + 16384;

    // QK^T: S (16 q x 64 kv) per wave
    f32x4 s[4];
#pragma unroll
    for (int i = 0; i < 4; ++i) s[i] = (f32x4){0.f, 0.f, 0.f, 0.f};
    __builtin_amdgcn_s_setprio(1);
#pragma unroll
    for (int kc = 0; kc < 4; ++kc) {
      const int d0b = (kc * 32 + (l >> 4) * 8) * 2;
#pragma unroll
      for (int ni = 0; ni < 4; ++ni) {
        const int row = ni * 16 + (l & 15);
        s16x8 kf = *(const s16x8*)(Kt + ((row * 256 + d0b) ^ ((row & 7) << 4)));
        s[ni] = mfma16(aq[kc], kf, s[ni]);
      }
    }
    __builtin_amdgcn_s_setprio(0);
    if (t >= nt - 2) {  // causal mask (QBLK=128 spans two KV tiles at diagonal)
      const int qpos_b = 2048 + qt * 128 + w * 16 + qrow16;
      const int kvcol = (l & 15);
#pragma unroll
      for (int ni = 0; ni < 4; ++ni) {
        const int kvpos = t * 64 + ni * 16 + kvcol;
#pragma unroll
        for (int rr = 0; rr < 4; ++rr)
          if (kvpos > qpos_b + rr) s[ni][rr] = -1e30f;
      }
    }
    // online softmax: row max (rows in 16-lane groups; reduce lane bits 0-3)
    float rm[4];
#pragma unroll
    for (int rr = 0; rr < 4; ++rr)
      rm[rr] = fmaxf(fmaxf(s[0][rr], s[1][rr]), fmaxf(s[2][rr], s[3][rr]));
#pragma unroll
    for (int rr = 0; rr < 4; ++rr) {
      float v = rm[rr];
      v = fmaxf(v, __shfl_xor(v, 1));
      v = fmaxf(v, __shfl_xor(v, 2));
      v = fmaxf(v, __shfl_xor(v, 4));
      v = fmaxf(v, __shfl_xor(v, 8));
      rm[rr] = v;
    }
    // defer-max (T13)
    const bool ok = (rm[0] <= m[0] + 8.f) && (rm[1] <= m[1] + 8.f) &&
                    (rm[2] <= m[2] + 8.f) && (rm[3] <= m[3] + 8.f);
    if (!__all(ok)) {
      float fs[4];
#pragma unroll
      for (int rr = 0; rr < 4; ++rr) {
        const float nm = fmaxf(m[rr], rm[rr]);
        fs[rr] = __expf(m[rr] - nm);
        m[rr] = nm;
      }
#pragma unroll
      for (int i = 0; i < 8; ++i)
#pragma unroll
        for (int rr = 0; rr < 4; ++rr) o[i][rr] *= fs[rr];
#pragma unroll
      for (int rr = 0; rr < 4; ++rr) ls[rr] *= fs[rr];
    }
    float rsum[4] = {0.f, 0.f, 0.f, 0.f};
#pragma unroll
    for (int ni = 0; ni < 4; ++ni)
#pragma unroll
      for (int rr = 0; rr < 4; ++rr) {
        const float p = __expf(s[ni][rr] - m[rr]);
        s[ni][rr] = p;
        rsum[rr] += p;
      }
#pragma unroll
    for (int rr = 0; rr < 4; ++rr) {
      float v = rsum[rr];
      v += __shfl_xor(v, 1);
      v += __shfl_xor(v, 2);
      v += __shfl_xor(v, 4);
      v += __shfl_xor(v, 8);
      ls[rr] += v;
    }
    // P -> LDS (bf16, swizzled per q-row); per-wave buffer
#pragma unroll
    for (int ni = 0; ni < 4; ++ni) {
      const int colb = (ni * 16 + (l & 15)) * 2;
#pragma unroll
      for (int rr = 0; rr < 4; ++rr) {
        const int q = qrow16 + rr;
        *(unsigned short*)(Pw + ((q * 128 + colb) ^ ((q & 7) << 4))) = f2bf(s[ni][rr]);
      }
    }
    // PV: ctx += P (16x64) * V^T (128x64)
    s16x8 pa[2];
#pragma unroll
    for (int kc2 = 0; kc2 < 2; ++kc2) {
      const int q = l & 15;
      const int kvb = (kc2 * 32 + (l >> 4) * 8) * 2;
      pa[kc2] = *(const s16x8*)(Pw + ((q * 128 + kvb) ^ ((q & 7) << 4)));
    }
    __builtin_amdgcn_s_setprio(1);
#pragma unroll
    for (int sub = 0; sub < 8; ++sub) {
      const int dd = sub * 16 + (l & 15);
#pragma unroll
      for (int kc2 = 0; kc2 < 2; ++kc2) {
        const int kvb = (kc2 * 32 + (l >> 4) * 8) * 2;
        s16x8 vf = *(const s16x8*)(Vt + ((dd * 128 + kvb) ^ ((dd & 7) << 4)));
        o[sub] = mfma16(pa[kc2], vf, o[sub]);
      }
    }
    __builtin_amdgcn_s_setprio(0);
    asm volatile("" ::: "memory");
    __builtin_amdgcn_s_barrier();   // all waves done reading buf[c]
    c ^= 1;
  }
  asm volatile("s_waitcnt vmcnt(0)" ::: "memory");  // drain last prefetch

  const int r0 = qt * 128 + w * 16 + qrow16;
  const int c0 = h * 128 + (l & 15);
#pragma unroll
  for (int sub = 0; sub < 8; ++sub)
#pragma unroll
    for (int rr = 0; rr < 4; ++rr) {
      const float v = o[sub][rr] / ls[rr];
      ctx[(size_t)(r0 + rr) * 4096 + c0 + sub * 16] = f2bf(v);
    }
}

// ---------------------------------------------------------------- launch
extern "C" void kernel_launch(void* const* d_in, const int* in_sizes, int n_in,
                              void* d_out, int out_size, void* d_ws, size_t ws_size,
                              hipStream_t stream) {
  (void)in_sizes; (void)n_in; (void)out_size; (void)ws_size;
  const float* hs     = (const float*)d_in[0];
  const int*   pos    = (const int*)d_in[1];
  const float* cachek = (const float*)d_in[2];
  const float* cachev = (const float*)d_in[3];
  const float* Wq     = (const float*)d_in[4];
  const float* bq     = (const float*)d_in[5];
  const float* Wk     = (const float*)d_in[6];
  const float* bk     = (const float*)d_in[7];
  const float* Wv     = (const float*)d_in[8];
  const float* bv     = (const float*)d_in[9];
  const float* Wo     = (const float*)d_in[10];

  float* out    = (float*)d_out;                     // 2048*4096
  float* keyout = out + (size_t)2048 * 4096;         // 8*4096*128
  float* valout = keyout + (size_t)8 * 4096 * 128;   // 8*4096*128

  char* ws = (char*)d_ws;
  unsigned short* hbf    = (unsigned short*)(ws + 0);
  unsigned short* qbf    = (unsigned short*)(ws + 0);
  char*           kswz   = ws + 16777216;
  char*           vswz   = ws + 25165824;
  unsigned short* wqkvbf = (unsigned short*)(ws + 33554432);
  unsigned short* wobf   = (unsigned short*)(ws + 134217728);
  float*          qkvf   = (float*)(ws + 167772160);
  unsigned short* ctxbf  = (unsigned short*)(ws + 167772160);
  float*          cost   = (float*)(ws + 218103808);
  float*          sint   = (float*)(ws + 218628096);
  float*          biasc  = (float*)(ws + 219152384);

  conv_all<<<2048, 256, 0, stream>>>((const float4*)hs, (const float4*)Wq,
                                     (const float4*)Wk, (const float4*)Wv,
                                     (const float4*)Wo, (const float4*)bq,
                                     (const float4*)bk, (const float4*)bv,
                                     (us4*)hbf, (us4*)wqkvbf, (us4*)wobf,
                                     (float4*)biasc);
  rope_table<<<512, 256, 0, stream>>>(pos, cost, sint);
  gemm_bt<<<dim3(48, 16), 256, 0, stream>>>(hbf, wqkvbf, biasc, qkvf, 2048, 6144, 8192);
  rope_scatter<<<2048, 256, 0, stream>>>(qkvf, cost, sint, cachek, cachev,
                                         keyout, valout, qbf, kswz, vswz);
  attn_fwd<<<512, 512, 0, stream>>>(qbf, kswz, vswz, ctxbf);
  gemm_bt<<<dim3(32, 16), 256, 0, stream>>>(ctxbf, wobf, nullptr, out, 2048, 4096, 4096);
}

// Round 4
// 713.841 us; speedup vs baseline: 1.1646x; 1.0703x over previous
//
#include <hip/hip_runtime.h>
#include <hip/hip_bf16.h>
#include <math.h>

typedef float f32x4 __attribute__((ext_vector_type(4)));
typedef short s16x8 __attribute__((ext_vector_type(8)));
typedef __bf16 bf16x8 __attribute__((ext_vector_type(8)));

__device__ __forceinline__ unsigned short f2bf(float f) {
  unsigned int u = __builtin_bit_cast(unsigned int, f);
  u += 0x7fffu + ((u >> 16) & 1u);
  return (unsigned short)(u >> 16);
}

__device__ __forceinline__ f32x4 mfma16(s16x8 a, s16x8 b, f32x4 c) {
  return __builtin_amdgcn_mfma_f32_16x16x32_bf16(
      __builtin_bit_cast(bf16x8, a), __builtin_bit_cast(bf16x8, b), c, 0, 0, 0);
}

#define GLDS(gp, lp) __builtin_amdgcn_global_load_lds(                      \
    (__attribute__((address_space(1))) void*)(gp),                          \
    (__attribute__((address_space(3))) void*)(lp), 16, 0, 0)

struct __attribute__((aligned(8))) us4 { unsigned short x, y, z, w; };
__device__ __forceinline__ us4 cvt4(float4 v) {
  us4 r; r.x = f2bf(v.x); r.y = f2bf(v.y); r.z = f2bf(v.z); r.w = f2bf(v.w);
  return r;
}

// ---------------------------------------------------------------- convert all
__global__ __launch_bounds__(256) void conv_all(
    const float4* __restrict__ h, const float4* __restrict__ wq,
    const float4* __restrict__ wk, const float4* __restrict__ wv,
    const float4* __restrict__ wo, const float4* __restrict__ bq,
    const float4* __restrict__ bk, const float4* __restrict__ bv,
    us4* __restrict__ hbf, us4* __restrict__ wqkvbf, us4* __restrict__ wobf,
    float4* __restrict__ biasc)
{
  const unsigned int U = 20973056u;
  const unsigned int stride = gridDim.x * blockDim.x;
  for (unsigned int u = blockIdx.x * blockDim.x + threadIdx.x; u < U; u += stride) {
    if (u < 4194304u) {
      hbf[u] = cvt4(h[u]);
    } else if (u < 12582912u) {
      unsigned int o = u - 4194304u;  wqkvbf[o] = cvt4(wq[o]);
    } else if (u < 14680064u) {
      unsigned int o = u - 12582912u; wqkvbf[8388608u + o] = cvt4(wk[o]);
    } else if (u < 16777216u) {
      unsigned int o = u - 14680064u; wqkvbf[10485760u + o] = cvt4(wv[o]);
    } else if (u < 20971520u) {
      unsigned int o = u - 16777216u; wobf[o] = cvt4(wo[o]);
    } else {
      unsigned int o = u - 20971520u;
      float4 v = (o < 1024u) ? bq[o] : (o < 1280u) ? bk[o - 1024u] : bv[o - 1280u];
      biasc[o] = v;
    }
  }
}

// ---------------------------------------------------------------- rope table
__global__ __launch_bounds__(256) void rope_table(const int* __restrict__ pos_ids,
                                                  float* __restrict__ cost,
                                                  float* __restrict__ sint)
{
  int idx = blockIdx.x * blockDim.x + threadIdx.x;
  if (idx >= 131072) return;
  int s = idx >> 6, i = idx & 63;
  double invf = exp(-((double)i / 64.0) * 9.210340371976184);  // ln(10000)
  double ang = (double)pos_ids[s] * invf;
  cost[idx] = (float)cos(ang);
  sint[idx] = (float)sin(ang);
}

// ---------------------------------------------------------------- GEMM 8-phase
// C = A * B^T + bias. A: MxK bf16 rm, B: NxK bf16 rm, C: MxN fp32.
// Tile 256 x BN (BN = NF*64), BK=64, 512 threads = 8 waves (2M x 4N).
// LDS: 2 bufs x {A 32KB | B BN*128B}; swizzle byte ^= (row&7)<<4 on stage-src
// and ds_read (T2). Burst-stage next tile at iter top; verify own loads with
// vmcnt(0) before the tile-end barrier (publish point). Per-phase raw barriers
// + setprio around the MFMA cluster (T3/T5).
template<int NF>
__global__ __launch_bounds__(512, 2) void gemm8p(const unsigned short* __restrict__ A,
                                                 const unsigned short* __restrict__ B,
                                                 const float* __restrict__ bias,
                                                 float* __restrict__ C,
                                                 int M, int N, int K)
{
  constexpr int BN = NF * 64;
  __shared__ char smem[131072];
  const int tid = threadIdx.x;
  const int l = tid & 63;
  const int w = tid >> 6;
  const int wm = w >> 2, wn = w & 3;
  const int wr = wm * 128;
  const int wc = wn * (16 * NF);
  const int lk16 = (l >> 4) * 16;

  // XCD-aware remap (gridDim.x % 8 == 0 for both instantiations)
  const int nwg = gridDim.x;
  const int s = (blockIdx.x & 7) * (nwg >> 3) + (blockIdx.x >> 3);
  const int NBX = N / BN;
  const int bx = s % NBX, by = s / NBX;
  const size_t arow0 = (size_t)by * 256;
  const size_t brow0 = (size_t)bx * BN;
  const size_t Kb = (size_t)K * 2;
  const char* Ab = (const char*)A;
  const char* Bb = (const char*)B;

  f32x4 acc[8][NF];
#pragma unroll
  for (int i = 0; i < 8; ++i)
#pragma unroll
    for (int j = 0; j < NF; ++j) acc[i][j] = (f32x4){0.f, 0.f, 0.f, 0.f};

  auto STAGE = [&](int t, char* buf) {
    const size_t k0b = (size_t)t * 128;
#pragma unroll
    for (int cc = 0; cc < 4; ++cc) {          // A tile: 256 rows x 128B
      const int ch = cc * 512 + tid;
      const int r = ch >> 3;
      const int c2s = ((ch & 7) * 16) ^ ((r & 7) << 4);
      GLDS(Ab + (arow0 + r) * Kb + k0b + c2s, buf + ch * 16);
    }
#pragma unroll
    for (int cc = 0; cc < NF; ++cc) {         // B tile: BN rows x 128B
      const int ch = cc * 512 + tid;
      const int r = ch >> 3;
      const int c2s = ((ch & 7) * 16) ^ ((r & 7) << 4);
      GLDS(Bb + (brow0 + r) * Kb + k0b + c2s, buf + 32768 + ch * 16);
    }
  };

  const int nt = K >> 6;
  STAGE(0, smem);
  asm volatile("s_waitcnt vmcnt(0)" ::: "memory");
  __builtin_amdgcn_s_barrier();

  for (int t = 0; t < nt; ++t) {
    char* cur = smem + (t & 1) * 65536;
    if (t + 1 < nt) STAGE(t + 1, smem + ((t + 1) & 1) * 65536);
    s16x8 bfr[NF][2];
#pragma unroll
    for (int qd = 0; qd < 4; ++qd) {
      s16x8 afr[2][2];
#pragma unroll
      for (int i = 0; i < 2; ++i)
#pragma unroll
        for (int k = 0; k < 2; ++k) {
          const int r = wr + (qd * 2 + i) * 16 + (l & 15);
          const int c2 = k * 64 + lk16;
          afr[i][k] = *(const s16x8*)(cur + (r * 128 + (c2 ^ ((r & 7) << 4))));
        }
      if (qd == 0) {
#pragma unroll
        for (int n = 0; n < NF; ++n)
#pragma unroll
          for (int k = 0; k < 2; ++k) {
            const int r = wc + n * 16 + (l & 15);
            const int c2 = k * 64 + lk16;
            bfr[n][k] = *(const s16x8*)(cur + 32768 + (r * 128 + (c2 ^ ((r & 7) << 4))));
          }
      }
      asm volatile("" ::: "memory");
      __builtin_amdgcn_s_barrier();
      __builtin_amdgcn_s_setprio(1);
#pragma unroll
      for (int i = 0; i < 2; ++i)
#pragma unroll
        for (int n = 0; n < NF; ++n)
#pragma unroll
          for (int k = 0; k < 2; ++k)
            acc[qd * 2 + i][n] = mfma16(afr[i][k], bfr[n][k], acc[qd * 2 + i][n]);
      __builtin_amdgcn_s_setprio(0);
      asm volatile("" ::: "memory");
      __builtin_amdgcn_s_barrier();
    }
    asm volatile("s_waitcnt vmcnt(0)" ::: "memory");  // own next-tile stages landed
    __builtin_amdgcn_s_barrier();                      // publish to all waves
  }

  const int r0 = (int)arow0 + wr + (l >> 4) * 4;
  const int c0 = (int)brow0 + wc + (l & 15);
#pragma unroll
  for (int mi = 0; mi < 8; ++mi) {
#pragma unroll
    for (int ni = 0; ni < NF; ++ni) {
      const int c = c0 + ni * 16;
      const float bvv = bias ? bias[c] : 0.f;
#pragma unroll
      for (int rr = 0; rr < 4; ++rr) {
        const int r = r0 + mi * 16 + rr;
        C[(size_t)r * N + c] = acc[mi][ni][rr] + bvv;
      }
    }
  }
}

// ---------------------------------------------------------------- RoPE + scatter
__global__ __launch_bounds__(256) void rope_scatter(
    const float* __restrict__ qkv, const float* __restrict__ cost,
    const float* __restrict__ sint, const float* __restrict__ cache_k,
    const float* __restrict__ cache_v, float* __restrict__ keyout,
    float* __restrict__ valout, unsigned short* __restrict__ qbf,
    char* __restrict__ kswz, char* __restrict__ vswz)
{
  const float rs = 0.08838834764831845f;  // 1/sqrt(128)
  const int stride = gridDim.x * blockDim.x;
  for (int idx = blockIdx.x * blockDim.x + threadIdx.x; idx < 11534336; idx += stride) {
    if (idx < 4194304) {                       // Q rope
      int i = idx & 63, hh = (idx >> 6) & 31, s = idx >> 11;
      const float* base = qkv + (size_t)s * 6144 + hh * 128 + i;
      float q1 = base[0], q2 = base[64];
      float c = cost[s * 64 + i], sn = sint[s * 64 + i];
      float o1 = (q1 * c - q2 * sn) * rs, o2 = (q2 * c + q1 * sn) * rs;
      unsigned short* qd = qbf + ((size_t)hh * 2048 + s) * 128 + i;
      qd[0] = f2bf(o1); qd[64] = f2bf(o2);
    } else if (idx < 5242880) {                // K rope + outputs
      int j = idx - 4194304;
      int i = j & 63, kh = (j >> 6) & 7, s = j >> 9;
      const float* base = qkv + (size_t)s * 6144 + 4096 + kh * 128 + i;
      float k1 = base[0], k2 = base[64];
      float c = cost[s * 64 + i], sn = sint[s * 64 + i];
      float o1 = k1 * c - k2 * sn, o2 = k2 * c + k1 * sn;
      float* kd = keyout + ((size_t)kh * 4096 + 2048 + s) * 128 + i;
      kd[0] = o1; kd[64] = o2;
      int t = 32 + (s >> 6), r = s & 63;
      char* tb = kswz + (size_t)(kh * 64 + t) * 16384;
      *(unsigned short*)(tb + ((r * 256 + i * 2) ^ ((r & 7) << 4))) = f2bf(o1);
      *(unsigned short*)(tb + ((r * 256 + (i + 64) * 2) ^ ((r & 7) << 4))) = f2bf(o2);
    } else if (idx < 7340032) {                // V new
      int j = idx - 5242880;
      int d = j & 127, kh = (j >> 7) & 7, s = j >> 10;
      float v = qkv[(size_t)s * 6144 + 5120 + kh * 128 + d];
      valout[((size_t)kh * 4096 + 2048 + s) * 128 + d] = v;
      int t = 32 + (s >> 6), c = s & 63;
      char* tb = vswz + (size_t)(kh * 64 + t) * 16384;
      *(unsigned short*)(tb + ((d * 128 + c * 2) ^ ((d & 7) << 4))) = f2bf(v);
    } else if (idx < 9437184) {                // cache K copy
      int j = idx - 7340032;
      int d = j & 127, s = (j >> 7) & 2047, kh = j >> 18;
      float v = cache_k[(size_t)(kh * 2048 + s) * 128 + d];
      keyout[((size_t)kh * 4096 + s) * 128 + d] = v;
      int t = s >> 6, r = s & 63;
      char* tb = kswz + (size_t)(kh * 64 + t) * 16384;
      *(unsigned short*)(tb + ((r * 256 + d * 2) ^ ((r & 7) << 4))) = f2bf(v);
    } else {                                   // cache V copy
      int j = idx - 9437184;
      int d = j & 127, s = (j >> 7) & 2047, kh = j >> 18;
      float v = cache_v[(size_t)(kh * 2048 + s) * 128 + d];
      valout[((size_t)kh * 4096 + s) * 128 + d] = v;
      int t = s >> 6, c = s & 63;
      char* tb = vswz + (size_t)(kh * 64 + t) * 16384;
      *(unsigned short*)(tb + ((d * 128 + c * 2) ^ ((d & 7) << 4))) = f2bf(v);
    }
  }
}

// ---------------------------------------------------------------- flash attention
// grid 512 blocks x 512 threads (8 waves). QBLK=128, KVBLK=64.
__global__ __launch_bounds__(512) void attn_fwd(const unsigned short* __restrict__ qbf,
                                                const char* __restrict__ kswz,
                                                const char* __restrict__ vswz,
                                                unsigned short* __restrict__ ctx)
{
  __shared__ char smem[81920];  // buf0: K16K|V16K; buf1: K16K|V16K; P 8x2K
  char* Ps = smem + 65536;
  const int tid = threadIdx.x;
  const int l = tid & 63;
  const int w = tid >> 6;                      // 0..7
  const int d = blockIdx.x;
  const int b = d >> 5;
  const int qt = (b < 8) ? b : 23 - b;         // 0..15, balanced pairs
  const int h = (d & 7) * 4 + ((d >> 3) & 3);  // kh = d%8
  const int kh = h >> 2;
  const int nt = 2 * qt + 34;
  const int qrow16 = (l >> 4) * 4;

  s16x8 aq[4];
  {
    const int qr = qt * 128 + w * 16 + (l & 15);
    const unsigned short* qp = qbf + ((size_t)h * 2048 + qr) * 128 + (l >> 4) * 8;
#pragma unroll
    for (int kc = 0; kc < 4; ++kc) aq[kc] = *(const s16x8*)(qp + kc * 32);
  }
  f32x4 o[8];
#pragma unroll
  for (int i = 0; i < 8; ++i) o[i] = (f32x4){0.f, 0.f, 0.f, 0.f};
  float m[4] = {-1e30f, -1e30f, -1e30f, -1e30f};
  float ls[4] = {0.f, 0.f, 0.f, 0.f};

  const char* kb0 = kswz + (size_t)kh * (64 * 16384);
  const char* vb0 = vswz + (size_t)kh * (64 * 16384);
  char* Pw = Ps + w * 2048;

  auto STAGE = [&](int t, int c) {
    const char* kb = kb0 + (size_t)t * 16384;
    const char* vb = vb0 + (size_t)t * 16384;
    char* Kt = smem + c * 32768;
    char* Vt = Kt + 16384;
#pragma unroll
    for (int j = 0; j < 2; ++j) {
      const int cw = j * 8 + w;                // 8 waves cover 16 chunks
      GLDS(kb + (cw * 64 + l) * 16, Kt + cw * 1024);
      GLDS(vb + (cw * 64 + l) * 16, Vt + cw * 1024);
    }
  };

  STAGE(0, 0);
  int c = 0;
  for (int t = 0; t < nt; ++t) {
    const int tn = (t + 1 < nt) ? t + 1 : t;
    STAGE(tn, c ^ 1);                       // 4 GLDS/wave in flight across barrier
    asm volatile("s_waitcnt vmcnt(4)" ::: "memory");  // own tile-t loads landed
    __builtin_amdgcn_s_barrier();
    asm volatile("" ::: "memory");
    const char* Kt = smem + c * 32768;
    const char* Vt = Kt + 16384;

    // QK^T: S (16 q x 64 kv) per wave
    f32x4 s[4];
#pragma unroll
    for (int i = 0; i < 4; ++i) s[i] = (f32x4){0.f, 0.f, 0.f, 0.f};
    __builtin_amdgcn_s_setprio(1);
#pragma unroll
    for (int kc = 0; kc < 4; ++kc) {
      const int d0b = (kc * 32 + (l >> 4) * 8) * 2;
#pragma unroll
      for (int ni = 0; ni < 4; ++ni) {
        const int row = ni * 16 + (l & 15);
        s16x8 kf = *(const s16x8*)(Kt + ((row * 256 + d0b) ^ ((row & 7) << 4)));
        s[ni] = mfma16(aq[kc], kf, s[ni]);
      }
    }
    __builtin_amdgcn_s_setprio(0);
    if (t >= nt - 2) {  // causal mask (QBLK=128 spans two KV tiles at diagonal)
      const int qpos_b = 2048 + qt * 128 + w * 16 + qrow16;
      const int kvcol = (l & 15);
#pragma unroll
      for (int ni = 0; ni < 4; ++ni) {
        const int kvpos = t * 64 + ni * 16 + kvcol;
#pragma unroll
        for (int rr = 0; rr < 4; ++rr)
          if (kvpos > qpos_b + rr) s[ni][rr] = -1e30f;
      }
    }
    // online softmax: row max (rows in 16-lane groups; reduce lane bits 0-3)
    float rm[4];
#pragma unroll
    for (int rr = 0; rr < 4; ++rr)
      rm[rr] = fmaxf(fmaxf(s[0][rr], s[1][rr]), fmaxf(s[2][rr], s[3][rr]));
#pragma unroll
    for (int rr = 0; rr < 4; ++rr) {
      float v = rm[rr];
      v = fmaxf(v, __shfl_xor(v, 1));
      v = fmaxf(v, __shfl_xor(v, 2));
      v = fmaxf(v, __shfl_xor(v, 4));
      v = fmaxf(v, __shfl_xor(v, 8));
      rm[rr] = v;
    }
    // defer-max (T13)
    const bool ok = (rm[0] <= m[0] + 8.f) && (rm[1] <= m[1] + 8.f) &&
                    (rm[2] <= m[2] + 8.f) && (rm[3] <= m[3] + 8.f);
    if (!__all(ok)) {
      float fs[4];
#pragma unroll
      for (int rr = 0; rr < 4; ++rr) {
        const float nm = fmaxf(m[rr], rm[rr]);
        fs[rr] = __expf(m[rr] - nm);
        m[rr] = nm;
      }
#pragma unroll
      for (int i = 0; i < 8; ++i)
#pragma unroll
        for (int rr = 0; rr < 4; ++rr) o[i][rr] *= fs[rr];
#pragma unroll
      for (int rr = 0; rr < 4; ++rr) ls[rr] *= fs[rr];
    }
    float rsum[4] = {0.f, 0.f, 0.f, 0.f};
#pragma unroll
    for (int ni = 0; ni < 4; ++ni)
#pragma unroll
      for (int rr = 0; rr < 4; ++rr) {
        const float p = __expf(s[ni][rr] - m[rr]);
        s[ni][rr] = p;
        rsum[rr] += p;
      }
#pragma unroll
    for (int rr = 0; rr < 4; ++rr) {
      float v = rsum[rr];
      v += __shfl_xor(v, 1);
      v += __shfl_xor(v, 2);
      v += __shfl_xor(v, 4);
      v += __shfl_xor(v, 8);
      ls[rr] += v;
    }
    // P -> LDS (bf16, swizzled per q-row); per-wave buffer
#pragma unroll
    for (int ni = 0; ni < 4; ++ni) {
      const int colb = (ni * 16 + (l & 15)) * 2;
#pragma unroll
      for (int rr = 0; rr < 4; ++rr) {
        const int q = qrow16 + rr;
        *(unsigned short*)(Pw + ((q * 128 + colb) ^ ((q & 7) << 4))) = f2bf(s[ni][rr]);
      }
    }
    // PV: ctx += P (16x64) * V^T (128x64)
    s16x8 pa[2];
#pragma unroll
    for (int kc2 = 0; kc2 < 2; ++kc2) {
      const int q = l & 15;
      const int kvb = (kc2 * 32 + (l >> 4) * 8) * 2;
      pa[kc2] = *(const s16x8*)(Pw + ((q * 128 + kvb) ^ ((q & 7) << 4)));
    }
    __builtin_amdgcn_s_setprio(1);
#pragma unroll
    for (int sub = 0; sub < 8; ++sub) {
      const int dd = sub * 16 + (l & 15);
#pragma unroll
      for (int kc2 = 0; kc2 < 2; ++kc2) {
        const int kvb = (kc2 * 32 + (l >> 4) * 8) * 2;
        s16x8 vf = *(const s16x8*)(Vt + ((dd * 128 + kvb) ^ ((dd & 7) << 4)));
        o[sub] = mfma16(pa[kc2], vf, o[sub]);
      }
    }
    __builtin_amdgcn_s_setprio(0);
    asm volatile("" ::: "memory");
    __builtin_amdgcn_s_barrier();   // all waves done reading buf[c]
    c ^= 1;
  }
  asm volatile("s_waitcnt vmcnt(0)" ::: "memory");  // drain last prefetch

  const int r0 = qt * 128 + w * 16 + qrow16;
  const int c0 = h * 128 + (l & 15);
#pragma unroll
  for (int sub = 0; sub < 8; ++sub)
#pragma unroll
    for (int rr = 0; rr < 4; ++rr) {
      const float v = o[sub][rr] / ls[rr];
      ctx[(size_t)(r0 + rr) * 4096 + c0 + sub * 16] = f2bf(v);
    }
}

// ---------------------------------------------------------------- launch
extern "C" void kernel_launch(void* const* d_in, const int* in_sizes, int n_in,
                              void* d_out, int out_size, void* d_ws, size_t ws_size,
                              hipStream_t stream) {
  (void)in_sizes; (void)n_in; (void)out_size; (void)ws_size;
  const float* hs     = (const float*)d_in[0];
  const int*   pos    = (const int*)d_in[1];
  const float* cachek = (const float*)d_in[2];
  const float* cachev = (const float*)d_in[3];
  const float* Wq     = (const float*)d_in[4];
  const float* bq     = (const float*)d_in[5];
  const float* Wk     = (const float*)d_in[6];
  const float* bk     = (const float*)d_in[7];
  const float* Wv     = (const float*)d_in[8];
  const float* bv     = (const float*)d_in[9];
  const float* Wo     = (const float*)d_in[10];

  float* out    = (float*)d_out;                     // 2048*4096
  float* keyout = out + (size_t)2048 * 4096;         // 8*4096*128
  float* valout = keyout + (size_t)8 * 4096 * 128;   // 8*4096*128

  char* ws = (char*)d_ws;
  unsigned short* hbf    = (unsigned short*)(ws + 0);
  unsigned short* qbf    = (unsigned short*)(ws + 0);
  char*           kswz   = ws + 16777216;
  char*           vswz   = ws + 25165824;
  unsigned short* wqkvbf = (unsigned short*)(ws + 33554432);
  unsigned short* wobf   = (unsigned short*)(ws + 134217728);
  float*          qkvf   = (float*)(ws + 167772160);
  unsigned short* ctxbf  = (unsigned short*)(ws + 167772160);
  float*          cost   = (float*)(ws + 218103808);
  float*          sint   = (float*)(ws + 218628096);
  float*          biasc  = (float*)(ws + 219152384);

  conv_all<<<2048, 256, 0, stream>>>((const float4*)hs, (const float4*)Wq,
                                     (const float4*)Wk, (const float4*)Wv,
                                     (const float4*)Wo, (const float4*)bq,
                                     (const float4*)bk, (const float4*)bv,
                                     (us4*)hbf, (us4*)wqkvbf, (us4*)wobf,
                                     (float4*)biasc);
  rope_table<<<512, 256, 0, stream>>>(pos, cost, sint);
  gemm8p<4><<<192, 512, 0, stream>>>(hbf, wqkvbf, biasc, qkvf, 2048, 6144, 8192);
  rope_scatter<<<2048, 256, 0, stream>>>(qkvf, cost, sint, cachek, cachev,
                                         keyout, valout, qbf, kswz, vswz);
  attn_fwd<<<512, 512, 0, stream>>>(qbf, kswz, vswz, ctxbf);
  gemm8p<2><<<256, 512, 0, stream>>>(ctxbf, wobf, nullptr, out, 2048, 4096, 4096);
}

// Round 5
// 668.321 us; speedup vs baseline: 1.2439x; 1.0681x over previous
//
#include <hip/hip_runtime.h>
#include <hip/hip_bf16.h>
#include <math.h>

typedef float f32x4 __attribute__((ext_vector_type(4)));
typedef short s16x8 __attribute__((ext_vector_type(8)));
typedef __bf16 bf16x8 __attribute__((ext_vector_type(8)));

__device__ __forceinline__ unsigned short f2bf(float f) {
  unsigned int u = __builtin_bit_cast(unsigned int, f);
  u += 0x7fffu + ((u >> 16) & 1u);
  return (unsigned short)(u >> 16);
}

__device__ __forceinline__ f32x4 mfma16(s16x8 a, s16x8 b, f32x4 c) {
  return __builtin_amdgcn_mfma_f32_16x16x32_bf16(
      __builtin_bit_cast(bf16x8, a), __builtin_bit_cast(bf16x8, b), c, 0, 0, 0);
}

#define GLDS(gp, lp) __builtin_amdgcn_global_load_lds(                      \
    (__attribute__((address_space(1))) void*)(gp),                          \
    (__attribute__((address_space(3))) void*)(lp), 16, 0, 0)

struct __attribute__((aligned(8))) us4 { unsigned short x, y, z, w; };
__device__ __forceinline__ us4 cvt4(float4 v) {
  us4 r; r.x = f2bf(v.x); r.y = f2bf(v.y); r.z = f2bf(v.z); r.w = f2bf(v.w);
  return r;
}

// ---------------------------------------------------------------- convert all
__global__ __launch_bounds__(256) void conv_all(
    const float4* __restrict__ h, const float4* __restrict__ wq,
    const float4* __restrict__ wk, const float4* __restrict__ wv,
    const float4* __restrict__ wo, const float4* __restrict__ bq,
    const float4* __restrict__ bk, const float4* __restrict__ bv,
    us4* __restrict__ hbf, us4* __restrict__ wqkvbf, us4* __restrict__ wobf,
    float4* __restrict__ biasc)
{
  const unsigned int U = 20973056u;
  const unsigned int stride = gridDim.x * blockDim.x;
  for (unsigned int u = blockIdx.x * blockDim.x + threadIdx.x; u < U; u += stride) {
    if (u < 4194304u) {
      hbf[u] = cvt4(h[u]);
    } else if (u < 12582912u) {
      unsigned int o = u - 4194304u;  wqkvbf[o] = cvt4(wq[o]);
    } else if (u < 14680064u) {
      unsigned int o = u - 12582912u; wqkvbf[8388608u + o] = cvt4(wk[o]);
    } else if (u < 16777216u) {
      unsigned int o = u - 14680064u; wqkvbf[10485760u + o] = cvt4(wv[o]);
    } else if (u < 20971520u) {
      unsigned int o = u - 16777216u; wobf[o] = cvt4(wo[o]);
    } else {
      unsigned int o = u - 20971520u;
      float4 v = (o < 1024u) ? bq[o] : (o < 1280u) ? bk[o - 1024u] : bv[o - 1280u];
      biasc[o] = v;
    }
  }
}

// ---------------------------------------------------------------- rope table
__global__ __launch_bounds__(256) void rope_table(const int* __restrict__ pos_ids,
                                                  float* __restrict__ cost,
                                                  float* __restrict__ sint)
{
  int idx = blockIdx.x * blockDim.x + threadIdx.x;
  if (idx >= 131072) return;
  int s = idx >> 6, i = idx & 63;
  double invf = exp(-((double)i / 64.0) * 9.210340371976184);  // ln(10000)
  double ang = (double)pos_ids[s] * invf;
  cost[idx] = (float)cos(ang);
  sint[idx] = (float)sin(ang);
}

// ---------------------------------------------------------------- GEMM 8-phase
// C = A * B^T + bias. A: MxK bf16 rm, B: NxK bf16 rm, C: MxN fp32.
// Tile 256 x BN (BN = NF*64), BK=64, 512 threads = 8 waves (2M x 4N).
// XCD mapping: s = (b%8)*(nwg/8)+b/8, then by = s % NBY, bx = s / NBY so each
// XCD owns a contiguous B-slice (large operand partitioned; small operand A
// shared via L3). T2 swizzle both-sides; burst-stage next tile; publish with
// own-loads drain + barrier.
template<int NF>
__global__ __launch_bounds__(512, 2) void gemm8p(const unsigned short* __restrict__ A,
                                                 const unsigned short* __restrict__ B,
                                                 const float* __restrict__ bias,
                                                 float* __restrict__ C,
                                                 int M, int N, int K)
{
  constexpr int BN = NF * 64;
  constexpr int BUFSZ = 32768 + BN * 128;
  __shared__ char smem[2 * BUFSZ];
  const int tid = threadIdx.x;
  const int l = tid & 63;
  const int w = tid >> 6;
  const int wm = w >> 2, wn = w & 3;
  const int wr = wm * 128;
  const int wc = wn * (16 * NF);
  const int lk16 = (l >> 4) * 16;

  const int nwg = gridDim.x;
  const int s = (blockIdx.x & 7) * (nwg >> 3) + (blockIdx.x >> 3);
  const int NBY = M >> 8;
  const int by = s % NBY, bx = s / NBY;   // XCD-contiguous s -> contiguous bx slice
  const size_t arow0 = (size_t)by * 256;
  const size_t brow0 = (size_t)bx * BN;
  const size_t Kb = (size_t)K * 2;
  const char* Ab = (const char*)A;
  const char* Bb = (const char*)B;

  f32x4 acc[8][NF];
#pragma unroll
  for (int i = 0; i < 8; ++i)
#pragma unroll
    for (int j = 0; j < NF; ++j) acc[i][j] = (f32x4){0.f, 0.f, 0.f, 0.f};

  auto STAGE = [&](int t, char* buf) {
    const size_t k0b = (size_t)t * 128;
#pragma unroll
    for (int cc = 0; cc < 4; ++cc) {          // A tile: 256 rows x 128B
      const int ch = cc * 512 + tid;
      const int r = ch >> 3;
      const int c2s = ((ch & 7) * 16) ^ ((r & 7) << 4);
      GLDS(Ab + (arow0 + r) * Kb + k0b + c2s, buf + ch * 16);
    }
#pragma unroll
    for (int cc = 0; cc < NF; ++cc) {         // B tile: BN rows x 128B
      const int ch = cc * 512 + tid;
      const int r = ch >> 3;
      const int c2s = ((ch & 7) * 16) ^ ((r & 7) << 4);
      GLDS(Bb + (brow0 + r) * Kb + k0b + c2s, buf + 32768 + ch * 16);
    }
  };

  const int nt = K >> 6;
  STAGE(0, smem);
  asm volatile("s_waitcnt vmcnt(0)" ::: "memory");
  __builtin_amdgcn_s_barrier();

  for (int t = 0; t < nt; ++t) {
    char* cur = smem + (t & 1) * BUFSZ;
    if (t + 1 < nt) STAGE(t + 1, smem + ((t + 1) & 1) * BUFSZ);
    s16x8 bfr[NF][2];
#pragma unroll
    for (int qd = 0; qd < 4; ++qd) {
      s16x8 afr[2][2];
#pragma unroll
      for (int i = 0; i < 2; ++i)
#pragma unroll
        for (int k = 0; k < 2; ++k) {
          const int r = wr + (qd * 2 + i) * 16 + (l & 15);
          const int c2 = k * 64 + lk16;
          afr[i][k] = *(const s16x8*)(cur + (r * 128 + (c2 ^ ((r & 7) << 4))));
        }
      if (qd == 0) {
#pragma unroll
        for (int n = 0; n < NF; ++n)
#pragma unroll
          for (int k = 0; k < 2; ++k) {
            const int r = wc + n * 16 + (l & 15);
            const int c2 = k * 64 + lk16;
            bfr[n][k] = *(const s16x8*)(cur + 32768 + (r * 128 + (c2 ^ ((r & 7) << 4))));
          }
      }
      asm volatile("" ::: "memory");
      __builtin_amdgcn_s_barrier();
      __builtin_amdgcn_s_setprio(1);
#pragma unroll
      for (int i = 0; i < 2; ++i)
#pragma unroll
        for (int n = 0; n < NF; ++n)
#pragma unroll
          for (int k = 0; k < 2; ++k)
            acc[qd * 2 + i][n] = mfma16(afr[i][k], bfr[n][k], acc[qd * 2 + i][n]);
      __builtin_amdgcn_s_setprio(0);
      asm volatile("" ::: "memory");
      __builtin_amdgcn_s_barrier();
    }
    asm volatile("s_waitcnt vmcnt(0)" ::: "memory");  // own next-tile stages landed
    __builtin_amdgcn_s_barrier();                      // publish to all waves
  }

  const int r0 = (int)arow0 + wr + (l >> 4) * 4;
  const int c0 = (int)brow0 + wc + (l & 15);
#pragma unroll
  for (int mi = 0; mi < 8; ++mi) {
#pragma unroll
    for (int ni = 0; ni < NF; ++ni) {
      const int c = c0 + ni * 16;
      const float bvv = bias ? bias[c] : 0.f;
#pragma unroll
      for (int rr = 0; rr < 4; ++rr) {
        const int r = r0 + mi * 16 + rr;
        C[(size_t)r * N + c] = acc[mi][ni][rr] + bvv;
      }
    }
  }
}

// ---------------------------------------------------------------- RoPE + scatter
__global__ __launch_bounds__(256) void rope_scatter(
    const float* __restrict__ qkv, const float* __restrict__ cost,
    const float* __restrict__ sint, const float* __restrict__ cache_k,
    const float* __restrict__ cache_v, float* __restrict__ keyout,
    float* __restrict__ valout, unsigned short* __restrict__ qbf,
    char* __restrict__ kswz, char* __restrict__ vswz)
{
  const float rs = 0.08838834764831845f;  // 1/sqrt(128)
  const int stride = gridDim.x * blockDim.x;
  for (int idx = blockIdx.x * blockDim.x + threadIdx.x; idx < 11534336; idx += stride) {
    if (idx < 4194304) {                       // Q rope
      int i = idx & 63, hh = (idx >> 6) & 31, s = idx >> 11;
      const float* base = qkv + (size_t)s * 6144 + hh * 128 + i;
      float q1 = base[0], q2 = base[64];
      float c = cost[s * 64 + i], sn = sint[s * 64 + i];
      float o1 = (q1 * c - q2 * sn) * rs, o2 = (q2 * c + q1 * sn) * rs;
      unsigned short* qd = qbf + ((size_t)hh * 2048 + s) * 128 + i;
      qd[0] = f2bf(o1); qd[64] = f2bf(o2);
    } else if (idx < 5242880) {                // K rope + outputs
      int j = idx - 4194304;
      int i = j & 63, kh = (j >> 6) & 7, s = j >> 9;
      const float* base = qkv + (size_t)s * 6144 + 4096 + kh * 128 + i;
      float k1 = base[0], k2 = base[64];
      float c = cost[s * 64 + i], sn = sint[s * 64 + i];
      float o1 = k1 * c - k2 * sn, o2 = k2 * c + k1 * sn;
      float* kd = keyout + ((size_t)kh * 4096 + 2048 + s) * 128 + i;
      kd[0] = o1; kd[64] = o2;
      int t = 32 + (s >> 6), r = s & 63;
      char* tb = kswz + (size_t)(kh * 64 + t) * 16384;
      *(unsigned short*)(tb + ((r * 256 + i * 2) ^ ((r & 7) << 4))) = f2bf(o1);
      *(unsigned short*)(tb + ((r * 256 + (i + 64) * 2) ^ ((r & 7) << 4))) = f2bf(o2);
    } else if (idx < 7340032) {                // V new
      int j = idx - 5242880;
      int d = j & 127, kh = (j >> 7) & 7, s = j >> 10;
      float v = qkv[(size_t)s * 6144 + 5120 + kh * 128 + d];
      valout[((size_t)kh * 4096 + 2048 + s) * 128 + d] = v;
      int t = 32 + (s >> 6), c = s & 63;
      char* tb = vswz + (size_t)(kh * 64 + t) * 16384;
      *(unsigned short*)(tb + ((d * 128 + c * 2) ^ ((d & 7) << 4))) = f2bf(v);
    } else if (idx < 9437184) {                // cache K copy
      int j = idx - 7340032;
      int d = j & 127, s = (j >> 7) & 2047, kh = j >> 18;
      float v = cache_k[(size_t)(kh * 2048 + s) * 128 + d];
      keyout[((size_t)kh * 4096 + s) * 128 + d] = v;
      int t = s >> 6, r = s & 63;
      char* tb = kswz + (size_t)(kh * 64 + t) * 16384;
      *(unsigned short*)(tb + ((r * 256 + d * 2) ^ ((r & 7) << 4))) = f2bf(v);
    } else {                                   // cache V copy
      int j = idx - 9437184;
      int d = j & 127, s = (j >> 7) & 2047, kh = j >> 18;
      float v = cache_v[(size_t)(kh * 2048 + s) * 128 + d];
      valout[((size_t)kh * 4096 + s) * 128 + d] = v;
      int t = s >> 6, c = s & 63;
      char* tb = vswz + (size_t)(kh * 64 + t) * 16384;
      *(unsigned short*)(tb + ((d * 128 + c * 2) ^ ((d & 7) << 4))) = f2bf(v);
    }
  }
}

// ---------------------------------------------------------------- flash attention
// grid 512 blocks x 512 threads (8 waves). QBLK=128, KVBLK=64.
__global__ __launch_bounds__(512) void attn_fwd(const unsigned short* __restrict__ qbf,
                                                const char* __restrict__ kswz,
                                                const char* __restrict__ vswz,
                                                unsigned short* __restrict__ ctx)
{
  __shared__ char smem[81920];  // buf0: K16K|V16K; buf1: K16K|V16K; P 8x2K
  char* Ps = smem + 65536;
  const int tid = threadIdx.x;
  const int l = tid & 63;
  const int w = tid >> 6;                      // 0..7
  const int d = blockIdx.x;
  const int b = d >> 5;
  const int qt = (b < 8) ? b : 23 - b;         // 0..15, balanced pairs
  const int h = (d & 7) * 4 + ((d >> 3) & 3);  // kh = d%8
  const int kh = h >> 2;
  const int nt = 2 * qt + 34;
  const int qrow16 = (l >> 4) * 4;

  s16x8 aq[4];
  {
    const int qr = qt * 128 + w * 16 + (l & 15);
    const unsigned short* qp = qbf + ((size_t)h * 2048 + qr) * 128 + (l >> 4) * 8;
#pragma unroll
    for (int kc = 0; kc < 4; ++kc) aq[kc] = *(const s16x8*)(qp + kc * 32);
  }
  f32x4 o[8];
#pragma unroll
  for (int i = 0; i < 8; ++i) o[i] = (f32x4){0.f, 0.f, 0.f, 0.f};
  float m[4] = {-1e30f, -1e30f, -1e30f, -1e30f};
  float ls[4] = {0.f, 0.f, 0.f, 0.f};

  const char* kb0 = kswz + (size_t)kh * (64 * 16384);
  const char* vb0 = vswz + (size_t)kh * (64 * 16384);
  char* Pw = Ps + w * 2048;

  auto STAGE = [&](int t, int c) {
    const char* kb = kb0 + (size_t)t * 16384;
    const char* vb = vb0 + (size_t)t * 16384;
    char* Kt = smem + c * 32768;
    char* Vt = Kt + 16384;
#pragma unroll
    for (int j = 0; j < 2; ++j) {
      const int cw = j * 8 + w;                // 8 waves cover 16 chunks
      GLDS(kb + (cw * 64 + l) * 16, Kt + cw * 1024);
      GLDS(vb + (cw * 64 + l) * 16, Vt + cw * 1024);
    }
  };

  STAGE(0, 0);
  int c = 0;
  for (int t = 0; t < nt; ++t) {
    const int tn = (t + 1 < nt) ? t + 1 : t;
    STAGE(tn, c ^ 1);                       // 4 GLDS/wave in flight across barrier
    asm volatile("s_waitcnt vmcnt(4)" ::: "memory");  // own tile-t loads landed
    __builtin_amdgcn_s_barrier();
    asm volatile("" ::: "memory");
    const char* Kt = smem + c * 32768;
    const char* Vt = Kt + 16384;

    // QK^T: S (16 q x 64 kv) per wave
    f32x4 s[4];
#pragma unroll
    for (int i = 0; i < 4; ++i) s[i] = (f32x4){0.f, 0.f, 0.f, 0.f};
    __builtin_amdgcn_s_setprio(1);
#pragma unroll
    for (int kc = 0; kc < 4; ++kc) {
      const int d0b = (kc * 32 + (l >> 4) * 8) * 2;
#pragma unroll
      for (int ni = 0; ni < 4; ++ni) {
        const int row = ni * 16 + (l & 15);
        s16x8 kf = *(const s16x8*)(Kt + ((row * 256 + d0b) ^ ((row & 7) << 4)));
        s[ni] = mfma16(aq[kc], kf, s[ni]);
      }
    }
    __builtin_amdgcn_s_setprio(0);
    if (t >= nt - 2) {  // causal mask (QBLK=128 spans two KV tiles at diagonal)
      const int qpos_b = 2048 + qt * 128 + w * 16 + qrow16;
      const int kvcol = (l & 15);
#pragma unroll
      for (int ni = 0; ni < 4; ++ni) {
        const int kvpos = t * 64 + ni * 16 + kvcol;
#pragma unroll
        for (int rr = 0; rr < 4; ++rr)
          if (kvpos > qpos_b + rr) s[ni][rr] = -1e30f;
      }
    }
    // online softmax: row max (rows in 16-lane groups; reduce lane bits 0-3)
    float rm[4];
#pragma unroll
    for (int rr = 0; rr < 4; ++rr)
      rm[rr] = fmaxf(fmaxf(s[0][rr], s[1][rr]), fmaxf(s[2][rr], s[3][rr]));
#pragma unroll
    for (int rr = 0; rr < 4; ++rr) {
      float v = rm[rr];
      v = fmaxf(v, __shfl_xor(v, 1));
      v = fmaxf(v, __shfl_xor(v, 2));
      v = fmaxf(v, __shfl_xor(v, 4));
      v = fmaxf(v, __shfl_xor(v, 8));
      rm[rr] = v;
    }
    // defer-max (T13)
    const bool ok = (rm[0] <= m[0] + 8.f) && (rm[1] <= m[1] + 8.f) &&
                    (rm[2] <= m[2] + 8.f) && (rm[3] <= m[3] + 8.f);
    if (!__all(ok)) {
      float fs[4];
#pragma unroll
      for (int rr = 0; rr < 4; ++rr) {
        const float nm = fmaxf(m[rr], rm[rr]);
        fs[rr] = __expf(m[rr] - nm);
        m[rr] = nm;
      }
#pragma unroll
      for (int i = 0; i < 8; ++i)
#pragma unroll
        for (int rr = 0; rr < 4; ++rr) o[i][rr] *= fs[rr];
#pragma unroll
      for (int rr = 0; rr < 4; ++rr) ls[rr] *= fs[rr];
    }
    float rsum[4] = {0.f, 0.f, 0.f, 0.f};
#pragma unroll
    for (int ni = 0; ni < 4; ++ni)
#pragma unroll
      for (int rr = 0; rr < 4; ++rr) {
        const float p = __expf(s[ni][rr] - m[rr]);
        s[ni][rr] = p;
        rsum[rr] += p;
      }
#pragma unroll
    for (int rr = 0; rr < 4; ++rr) {
      float v = rsum[rr];
      v += __shfl_xor(v, 1);
      v += __shfl_xor(v, 2);
      v += __shfl_xor(v, 4);
      v += __shfl_xor(v, 8);
      ls[rr] += v;
    }
    // P -> LDS (bf16, swizzled per q-row); per-wave buffer
#pragma unroll
    for (int ni = 0; ni < 4; ++ni) {
      const int colb = (ni * 16 + (l & 15)) * 2;
#pragma unroll
      for (int rr = 0; rr < 4; ++rr) {
        const int q = qrow16 + rr;
        *(unsigned short*)(Pw + ((q * 128 + colb) ^ ((q & 7) << 4))) = f2bf(s[ni][rr]);
      }
    }
    // PV: ctx += P (16x64) * V^T (128x64)
    s16x8 pa[2];
#pragma unroll
    for (int kc2 = 0; kc2 < 2; ++kc2) {
      const int q = l & 15;
      const int kvb = (kc2 * 32 + (l >> 4) * 8) * 2;
      pa[kc2] = *(const s16x8*)(Pw + ((q * 128 + kvb) ^ ((q & 7) << 4)));
    }
    __builtin_amdgcn_s_setprio(1);
#pragma unroll
    for (int sub = 0; sub < 8; ++sub) {
      const int dd = sub * 16 + (l & 15);
#pragma unroll
      for (int kc2 = 0; kc2 < 2; ++kc2) {
        const int kvb = (kc2 * 32 + (l >> 4) * 8) * 2;
        s16x8 vf = *(const s16x8*)(Vt + ((dd * 128 + kvb) ^ ((dd & 7) << 4)));
        o[sub] = mfma16(pa[kc2], vf, o[sub]);
      }
    }
    __builtin_amdgcn_s_setprio(0);
    asm volatile("" ::: "memory");
    __builtin_amdgcn_s_barrier();   // all waves done reading buf[c]
    c ^= 1;
  }
  asm volatile("s_waitcnt vmcnt(0)" ::: "memory");  // drain last prefetch

  const int r0 = qt * 128 + w * 16 + qrow16;
  const int c0 = h * 128 + (l & 15);
#pragma unroll
  for (int sub = 0; sub < 8; ++sub)
#pragma unroll
    for (int rr = 0; rr < 4; ++rr) {
      const float v = o[sub][rr] / ls[rr];
      ctx[(size_t)(r0 + rr) * 4096 + c0 + sub * 16] = f2bf(v);
    }
}

// ---------------------------------------------------------------- launch
extern "C" void kernel_launch(void* const* d_in, const int* in_sizes, int n_in,
                              void* d_out, int out_size, void* d_ws, size_t ws_size,
                              hipStream_t stream) {
  (void)in_sizes; (void)n_in; (void)out_size; (void)ws_size;
  const float* hs     = (const float*)d_in[0];
  const int*   pos    = (const int*)d_in[1];
  const float* cachek = (const float*)d_in[2];
  const float* cachev = (const float*)d_in[3];
  const float* Wq     = (const float*)d_in[4];
  const float* bq     = (const float*)d_in[5];
  const float* Wk     = (const float*)d_in[6];
  const float* bk     = (const float*)d_in[7];
  const float* Wv     = (const float*)d_in[8];
  const float* bv     = (const float*)d_in[9];
  const float* Wo     = (const float*)d_in[10];

  float* out    = (float*)d_out;                     // 2048*4096
  float* keyout = out + (size_t)2048 * 4096;         // 8*4096*128
  float* valout = keyout + (size_t)8 * 4096 * 128;   // 8*4096*128

  char* ws = (char*)d_ws;
  unsigned short* hbf    = (unsigned short*)(ws + 0);
  unsigned short* qbf    = (unsigned short*)(ws + 0);
  char*           kswz   = ws + 16777216;
  char*           vswz   = ws + 25165824;
  unsigned short* wqkvbf = (unsigned short*)(ws + 33554432);
  unsigned short* wobf   = (unsigned short*)(ws + 134217728);
  float*          qkvf   = (float*)(ws + 167772160);
  unsigned short* ctxbf  = (unsigned short*)(ws + 167772160);
  float*          cost   = (float*)(ws + 218103808);
  float*          sint   = (float*)(ws + 218628096);
  float*          biasc  = (float*)(ws + 219152384);

  conv_all<<<2048, 256, 0, stream>>>((const float4*)hs, (const float4*)Wq,
                                     (const float4*)Wk, (const float4*)Wv,
                                     (const float4*)Wo, (const float4*)bq,
                                     (const float4*)bk, (const float4*)bv,
                                     (us4*)hbf, (us4*)wqkvbf, (us4*)wobf,
                                     (float4*)biasc);
  rope_table<<<512, 256, 0, stream>>>(pos, cost, sint);
  gemm8p<3><<<256, 512, 0, stream>>>(hbf, wqkvbf, biasc, qkvf, 2048, 6144, 8192);
  rope_scatter<<<2048, 256, 0, stream>>>(qkvf, cost, sint, cachek, cachev,
                                         keyout, valout, qbf, kswz, vswz);
  attn_fwd<<<512, 512, 0, stream>>>(qbf, kswz, vswz, ctxbf);
  gemm8p<2><<<256, 512, 0, stream>>>(ctxbf, wobf, nullptr, out, 2048, 4096, 4096);
}

// Round 6
// 636.993 us; speedup vs baseline: 1.3051x; 1.0492x over previous
//
#include <hip/hip_runtime.h>
#include <hip/hip_bf16.h>
#include <math.h>

typedef float f32x4 __attribute__((ext_vector_type(4)));
typedef short s16x8 __attribute__((ext_vector_type(8)));
typedef __bf16 bf16x8 __attribute__((ext_vector_type(8)));

__device__ __forceinline__ unsigned short f2bf(float f) {
  return __builtin_bit_cast(unsigned short, (__bf16)f);  // hw v_cvt_pk_bf16_f32, RTNE
}

__device__ __forceinline__ f32x4 mfma16(s16x8 a, s16x8 b, f32x4 c) {
  return __builtin_amdgcn_mfma_f32_16x16x32_bf16(
      __builtin_bit_cast(bf16x8, a), __builtin_bit_cast(bf16x8, b), c, 0, 0, 0);
}

#define GLDS(gp, lp) __builtin_amdgcn_global_load_lds(                      \
    (__attribute__((address_space(1))) void*)(gp),                          \
    (__attribute__((address_space(3))) void*)(lp), 16, 0, 0)

struct __attribute__((aligned(8))) us4 { unsigned short x, y, z, w; };
__device__ __forceinline__ us4 cvt4(float4 v) {
  us4 r; r.x = f2bf(v.x); r.y = f2bf(v.y); r.z = f2bf(v.z); r.w = f2bf(v.w);
  return r;
}

// ---------------------------------------------------------------- convert all
__global__ __launch_bounds__(256) void conv_all(
    const float4* __restrict__ h, const float4* __restrict__ wq,
    const float4* __restrict__ wk, const float4* __restrict__ wv,
    const float4* __restrict__ wo, const float4* __restrict__ bq,
    const float4* __restrict__ bk, const float4* __restrict__ bv,
    us4* __restrict__ hbf, us4* __restrict__ wqkvbf, us4* __restrict__ wobf,
    float4* __restrict__ biasc)
{
  const unsigned int U = 20973056u;
  const unsigned int stride = gridDim.x * blockDim.x;
  for (unsigned int u = blockIdx.x * blockDim.x + threadIdx.x; u < U; u += stride) {
    if (u < 4194304u) {
      hbf[u] = cvt4(h[u]);
    } else if (u < 12582912u) {
      unsigned int o = u - 4194304u;  wqkvbf[o] = cvt4(wq[o]);
    } else if (u < 14680064u) {
      unsigned int o = u - 12582912u; wqkvbf[8388608u + o] = cvt4(wk[o]);
    } else if (u < 16777216u) {
      unsigned int o = u - 14680064u; wqkvbf[10485760u + o] = cvt4(wv[o]);
    } else if (u < 20971520u) {
      unsigned int o = u - 16777216u; wobf[o] = cvt4(wo[o]);
    } else {
      unsigned int o = u - 20971520u;
      float4 v = (o < 1024u) ? bq[o] : (o < 1280u) ? bk[o - 1024u] : bv[o - 1280u];
      biasc[o] = v;
    }
  }
}

// ---------------------------------------------------------------- rope table
__global__ __launch_bounds__(256) void rope_table(const int* __restrict__ pos_ids,
                                                  float* __restrict__ cost,
                                                  float* __restrict__ sint)
{
  int idx = blockIdx.x * blockDim.x + threadIdx.x;
  if (idx >= 131072) return;
  int s = idx >> 6, i = idx & 63;
  double invf = exp(-((double)i / 64.0) * 9.210340371976184);  // ln(10000)
  double ang = (double)pos_ids[s] * invf;
  cost[idx] = (float)cos(ang);
  sint[idx] = (float)sin(ang);
}

// ---------------------------------------------------------------- GEMM 8-phase
// C = A * B^T + bias. Tile 256 x (NF*64), BK=64, 512 threads = 8 waves.
template<int NF>
__global__ __launch_bounds__(512, 2) void gemm8p(const unsigned short* __restrict__ A,
                                                 const unsigned short* __restrict__ B,
                                                 const float* __restrict__ bias,
                                                 float* __restrict__ C,
                                                 int M, int N, int K)
{
  constexpr int BN = NF * 64;
  constexpr int BUFSZ = 32768 + BN * 128;
  __shared__ char smem[2 * BUFSZ];
  const int tid = threadIdx.x;
  const int l = tid & 63;
  const int w = tid >> 6;
  const int wm = w >> 2, wn = w & 3;
  const int wr = wm * 128;
  const int wc = wn * (16 * NF);
  const int lk16 = (l >> 4) * 16;

  const int nwg = gridDim.x;
  const int s = (blockIdx.x & 7) * (nwg >> 3) + (blockIdx.x >> 3);
  const int NBY = M >> 8;
  const int by = s % NBY, bx = s / NBY;   // XCD-contiguous s -> contiguous bx slice
  const size_t arow0 = (size_t)by * 256;
  const size_t brow0 = (size_t)bx * BN;
  const size_t Kb = (size_t)K * 2;
  const char* Ab = (const char*)A;
  const char* Bb = (const char*)B;

  f32x4 acc[8][NF];
#pragma unroll
  for (int i = 0; i < 8; ++i)
#pragma unroll
    for (int j = 0; j < NF; ++j) acc[i][j] = (f32x4){0.f, 0.f, 0.f, 0.f};

  auto STAGE = [&](int t, char* buf) {
    const size_t k0b = (size_t)t * 128;
#pragma unroll
    for (int cc = 0; cc < 4; ++cc) {          // A tile: 256 rows x 128B
      const int ch = cc * 512 + tid;
      const int r = ch >> 3;
      const int c2s = ((ch & 7) * 16) ^ ((r & 7) << 4);
      GLDS(Ab + (arow0 + r) * Kb + k0b + c2s, buf + ch * 16);
    }
#pragma unroll
    for (int cc = 0; cc < NF; ++cc) {         // B tile: BN rows x 128B
      const int ch = cc * 512 + tid;
      const int r = ch >> 3;
      const int c2s = ((ch & 7) * 16) ^ ((r & 7) << 4);
      GLDS(Bb + (brow0 + r) * Kb + k0b + c2s, buf + 32768 + ch * 16);
    }
  };

  const int nt = K >> 6;
  STAGE(0, smem);
  asm volatile("s_waitcnt vmcnt(0)" ::: "memory");
  __builtin_amdgcn_s_barrier();

  for (int t = 0; t < nt; ++t) {
    char* cur = smem + (t & 1) * BUFSZ;
    if (t + 1 < nt) STAGE(t + 1, smem + ((t + 1) & 1) * BUFSZ);
    s16x8 bfr[NF][2];
#pragma unroll
    for (int qd = 0; qd < 4; ++qd) {
      s16x8 afr[2][2];
#pragma unroll
      for (int i = 0; i < 2; ++i)
#pragma unroll
        for (int k = 0; k < 2; ++k) {
          const int r = wr + (qd * 2 + i) * 16 + (l & 15);
          const int c2 = k * 64 + lk16;
          afr[i][k] = *(const s16x8*)(cur + (r * 128 + (c2 ^ ((r & 7) << 4))));
        }
      if (qd == 0) {
#pragma unroll
        for (int n = 0; n < NF; ++n)
#pragma unroll
          for (int k = 0; k < 2; ++k) {
            const int r = wc + n * 16 + (l & 15);
            const int c2 = k * 64 + lk16;
            bfr[n][k] = *(const s16x8*)(cur + 32768 + (r * 128 + (c2 ^ ((r & 7) << 4))));
          }
      }
      asm volatile("" ::: "memory");
      __builtin_amdgcn_s_barrier();
      __builtin_amdgcn_s_setprio(1);
#pragma unroll
      for (int i = 0; i < 2; ++i)
#pragma unroll
        for (int n = 0; n < NF; ++n)
#pragma unroll
          for (int k = 0; k < 2; ++k)
            acc[qd * 2 + i][n] = mfma16(afr[i][k], bfr[n][k], acc[qd * 2 + i][n]);
      __builtin_amdgcn_s_setprio(0);
      asm volatile("" ::: "memory");
      __builtin_amdgcn_s_barrier();
    }
    asm volatile("s_waitcnt vmcnt(0)" ::: "memory");  // own next-tile stages landed
    __builtin_amdgcn_s_barrier();                      // publish to all waves
  }

  const int r0 = (int)arow0 + wr + (l >> 4) * 4;
  const int c0 = (int)brow0 + wc + (l & 15);
#pragma unroll
  for (int mi = 0; mi < 8; ++mi) {
#pragma unroll
    for (int ni = 0; ni < NF; ++ni) {
      const int c = c0 + ni * 16;
      const float bvv = bias ? bias[c] : 0.f;
#pragma unroll
      for (int rr = 0; rr < 4; ++rr) {
        const int r = r0 + mi * 16 + rr;
        C[(size_t)r * N + c] = acc[mi][ni][rr] + bvv;
      }
    }
  }
}

// ---------------------------------------------------------------- RoPE + scatter
__global__ __launch_bounds__(256) void rope_scatter(
    const float* __restrict__ qkv, const float* __restrict__ cost,
    const float* __restrict__ sint, const float* __restrict__ cache_k,
    const float* __restrict__ cache_v, float* __restrict__ keyout,
    float* __restrict__ valout, unsigned short* __restrict__ qbf,
    char* __restrict__ kswz, char* __restrict__ vswz)
{
  const float rs = 0.08838834764831845f;  // 1/sqrt(128)
  const int stride = gridDim.x * blockDim.x;
  for (int idx = blockIdx.x * blockDim.x + threadIdx.x; idx < 11534336; idx += stride) {
    if (idx < 4194304) {                       // Q rope
      int i = idx & 63, hh = (idx >> 6) & 31, s = idx >> 11;
      const float* base = qkv + (size_t)s * 6144 + hh * 128 + i;
      float q1 = base[0], q2 = base[64];
      float c = cost[s * 64 + i], sn = sint[s * 64 + i];
      float o1 = (q1 * c - q2 * sn) * rs, o2 = (q2 * c + q1 * sn) * rs;
      unsigned short* qd = qbf + ((size_t)hh * 2048 + s) * 128 + i;
      qd[0] = f2bf(o1); qd[64] = f2bf(o2);
    } else if (idx < 5242880) {                // K rope + outputs
      int j = idx - 4194304;
      int i = j & 63, kh = (j >> 6) & 7, s = j >> 9;
      const float* base = qkv + (size_t)s * 6144 + 4096 + kh * 128 + i;
      float k1 = base[0], k2 = base[64];
      float c = cost[s * 64 + i], sn = sint[s * 64 + i];
      float o1 = k1 * c - k2 * sn, o2 = k2 * c + k1 * sn;
      float* kd = keyout + ((size_t)kh * 4096 + 2048 + s) * 128 + i;
      kd[0] = o1; kd[64] = o2;
      int t = 32 + (s >> 6), r = s & 63;
      char* tb = kswz + (size_t)(kh * 64 + t) * 16384;
      *(unsigned short*)(tb + ((r * 256 + i * 2) ^ ((r & 7) << 4))) = f2bf(o1);
      *(unsigned short*)(tb + ((r * 256 + (i + 64) * 2) ^ ((r & 7) << 4))) = f2bf(o2);
    } else if (idx < 7340032) {                // V new
      int j = idx - 5242880;
      int d = j & 127, kh = (j >> 7) & 7, s = j >> 10;
      float v = qkv[(size_t)s * 6144 + 5120 + kh * 128 + d];
      valout[((size_t)kh * 4096 + 2048 + s) * 128 + d] = v;
      int t = 32 + (s >> 6), c = s & 63;
      char* tb = vswz + (size_t)(kh * 64 + t) * 16384;
      *(unsigned short*)(tb + ((d * 128 + c * 2) ^ ((d & 7) << 4))) = f2bf(v);
    } else if (idx < 9437184) {                // cache K copy
      int j = idx - 7340032;
      int d = j & 127, s = (j >> 7) & 2047, kh = j >> 18;
      float v = cache_k[(size_t)(kh * 2048 + s) * 128 + d];
      keyout[((size_t)kh * 4096 + s) * 128 + d] = v;
      int t = s >> 6, r = s & 63;
      char* tb = kswz + (size_t)(kh * 64 + t) * 16384;
      *(unsigned short*)(tb + ((r * 256 + d * 2) ^ ((r & 7) << 4))) = f2bf(v);
    } else {                                   // cache V copy
      int j = idx - 9437184;
      int d = j & 127, s = (j >> 7) & 2047, kh = j >> 18;
      float v = cache_v[(size_t)(kh * 2048 + s) * 128 + d];
      valout[((size_t)kh * 4096 + s) * 128 + d] = v;
      int t = s >> 6, c = s & 63;
      char* tb = vswz + (size_t)(kh * 64 + t) * 16384;
      *(unsigned short*)(tb + ((d * 128 + c * 2) ^ ((d & 7) << 4))) = f2bf(v);
    }
  }
}

// ---------------------------------------------------------------- flash attention
// grid 512 blocks x 512 threads (8 waves). QBLK=128, KVBLK=64.
// ONE barrier per tile: vmcnt(0) -> barrier -> STAGE(t+1, c^1) -> compute buf[c].
// Barrier proves (a) tile-t loads of all waves drained, (b) all waves finished
// reading buf[c^1] at t-1, so staging into it after the barrier is race-free.
__global__ __launch_bounds__(512) void attn_fwd(const unsigned short* __restrict__ qbf,
                                                const char* __restrict__ kswz,
                                                const char* __restrict__ vswz,
                                                unsigned short* __restrict__ ctx)
{
  __shared__ char smem[81920];  // buf0: K16K|V16K; buf1: K16K|V16K; P 8x2K
  char* Ps = smem + 65536;
  const int tid = threadIdx.x;
  const int l = tid & 63;
  const int w = tid >> 6;                      // 0..7
  const int d = blockIdx.x;
  const int b = d >> 5;
  const int qt = (b < 8) ? b : 23 - b;         // 0..15, balanced pairs
  const int h = (d & 7) * 4 + ((d >> 3) & 3);  // kh = d%8
  const int kh = h >> 2;
  const int nt = 2 * qt + 34;
  const int qrow16 = (l >> 4) * 4;
  const float L2E = 1.44269504f;

  s16x8 aq[4];
  {
    const int qr = qt * 128 + w * 16 + (l & 15);
    const unsigned short* qp = qbf + ((size_t)h * 2048 + qr) * 128 + (l >> 4) * 8;
#pragma unroll
    for (int kc = 0; kc < 4; ++kc) aq[kc] = *(const s16x8*)(qp + kc * 32);
  }
  f32x4 o[8];
#pragma unroll
  for (int i = 0; i < 8; ++i) o[i] = (f32x4){0.f, 0.f, 0.f, 0.f};
  float m[4]  = {-1e30f, -1e30f, -1e30f, -1e30f};
  float m2[4] = {-1e30f, -1e30f, -1e30f, -1e30f};   // m * log2(e)
  float ls[4] = {0.f, 0.f, 0.f, 0.f};               // lane-partial row sums

  const char* kb0 = kswz + (size_t)kh * (64 * 16384);
  const char* vb0 = vswz + (size_t)kh * (64 * 16384);
  char* Pw = Ps + w * 2048;

  auto STAGE = [&](int t, int c) {
    const char* kb = kb0 + (size_t)t * 16384;
    const char* vb = vb0 + (size_t)t * 16384;
    char* Kt = smem + c * 32768;
    char* Vt = Kt + 16384;
#pragma unroll
    for (int j = 0; j < 2; ++j) {
      const int cw = j * 8 + w;                // 8 waves cover 16 chunks
      GLDS(kb + (cw * 64 + l) * 16, Kt + cw * 1024);
      GLDS(vb + (cw * 64 + l) * 16, Vt + cw * 1024);
    }
  };

  STAGE(0, 0);
  int c = 0;
  for (int t = 0; t < nt; ++t) {
    asm volatile("s_waitcnt vmcnt(0)" ::: "memory");  // own tile-t loads landed
    __builtin_amdgcn_s_barrier();                     // publish t; t-1 reads done
    asm volatile("" ::: "memory");
    if (t + 1 < nt) STAGE(t + 1, c ^ 1);              // loads fly under compute
    const char* Kt = smem + c * 32768;
    const char* Vt = Kt + 16384;

    // QK^T: S (16 q x 64 kv) per wave
    f32x4 s[4];
#pragma unroll
    for (int i = 0; i < 4; ++i) s[i] = (f32x4){0.f, 0.f, 0.f, 0.f};
    __builtin_amdgcn_s_setprio(1);
#pragma unroll
    for (int kc = 0; kc < 4; ++kc) {
      const int d0b = (kc * 32 + (l >> 4) * 8) * 2;
#pragma unroll
      for (int ni = 0; ni < 4; ++ni) {
        const int row = ni * 16 + (l & 15);
        s16x8 kf = *(const s16x8*)(Kt + ((row * 256 + d0b) ^ ((row & 7) << 4)));
        s[ni] = mfma16(aq[kc], kf, s[ni]);
      }
    }
    __builtin_amdgcn_s_setprio(0);
    if (t >= nt - 2) {  // causal mask (QBLK=128 spans two KV tiles at diagonal)
      const int qpos_b = 2048 + qt * 128 + w * 16 + qrow16;
      const int kvcol = (l & 15);
#pragma unroll
      for (int ni = 0; ni < 4; ++ni) {
        const int kvpos = t * 64 + ni * 16 + kvcol;
#pragma unroll
        for (int rr = 0; rr < 4; ++rr)
          if (kvpos > qpos_b + rr) s[ni][rr] = -1e30f;
      }
    }
    // online softmax: row max (16-lane groups; reduce lane bits 0-3)
    float rm[4];
#pragma unroll
    for (int rr = 0; rr < 4; ++rr)
      rm[rr] = fmaxf(fmaxf(s[0][rr], s[1][rr]), fmaxf(s[2][rr], s[3][rr]));
#pragma unroll
    for (int rr = 0; rr < 4; ++rr) {
      float v = rm[rr];
      v = fmaxf(v, __shfl_xor(v, 1));
      v = fmaxf(v, __shfl_xor(v, 2));
      v = fmaxf(v, __shfl_xor(v, 4));
      v = fmaxf(v, __shfl_xor(v, 8));
      rm[rr] = v;
    }
    // defer-max (T13)
    const bool ok = (rm[0] <= m[0] + 8.f) && (rm[1] <= m[1] + 8.f) &&
                    (rm[2] <= m[2] + 8.f) && (rm[3] <= m[3] + 8.f);
    if (!__all(ok)) {
      float fs[4];
#pragma unroll
      for (int rr = 0; rr < 4; ++rr) {
        const float nm = fmaxf(m[rr], rm[rr]);
        fs[rr] = __builtin_amdgcn_exp2f((m[rr] - nm) * L2E);
        m[rr] = nm;
        m2[rr] = nm * L2E;
      }
#pragma unroll
      for (int i = 0; i < 8; ++i)
#pragma unroll
        for (int rr = 0; rr < 4; ++rr) o[i][rr] *= fs[rr];
#pragma unroll
      for (int rr = 0; rr < 4; ++rr) ls[rr] *= fs[rr];
    }
    // exp + P -> LDS (bf16, swizzled per q-row); lane-partial row sums
#pragma unroll
    for (int ni = 0; ni < 4; ++ni) {
      const int colb = (ni * 16 + (l & 15)) * 2;
#pragma unroll
      for (int rr = 0; rr < 4; ++rr) {
        const float p = __builtin_amdgcn_exp2f(__builtin_fmaf(s[ni][rr], L2E, -m2[rr]));
        ls[rr] += p;
        const int q = qrow16 + rr;
        *(__bf16*)(Pw + ((q * 128 + colb) ^ ((q & 7) << 4))) = (__bf16)p;
      }
    }
    // PV: ctx += P (16x64) * V^T (128x64)
    s16x8 pa[2];
#pragma unroll
    for (int kc2 = 0; kc2 < 2; ++kc2) {
      const int q = l & 15;
      const int kvb = (kc2 * 32 + (l >> 4) * 8) * 2;
      pa[kc2] = *(const s16x8*)(Pw + ((q * 128 + kvb) ^ ((q & 7) << 4)));
    }
    __builtin_amdgcn_s_setprio(1);
#pragma unroll
    for (int sub = 0; sub < 8; ++sub) {
      const int dd = sub * 16 + (l & 15);
#pragma unroll
      for (int kc2 = 0; kc2 < 2; ++kc2) {
        const int kvb = (kc2 * 32 + (l >> 4) * 8) * 2;
        s16x8 vf = *(const s16x8*)(Vt + ((dd * 128 + kvb) ^ ((dd & 7) << 4)));
        o[sub] = mfma16(pa[kc2], vf, o[sub]);
      }
    }
    __builtin_amdgcn_s_setprio(0);
    asm volatile("" ::: "memory");
    c ^= 1;
  }

  // epilogue: reduce lane-partial sums once, then scale
#pragma unroll
  for (int rr = 0; rr < 4; ++rr) {
    float v = ls[rr];
    v += __shfl_xor(v, 1);
    v += __shfl_xor(v, 2);
    v += __shfl_xor(v, 4);
    v += __shfl_xor(v, 8);
    ls[rr] = 1.0f / v;
  }
  const int r0 = qt * 128 + w * 16 + qrow16;
  const int c0 = h * 128 + (l & 15);
#pragma unroll
  for (int sub = 0; sub < 8; ++sub)
#pragma unroll
    for (int rr = 0; rr < 4; ++rr) {
      const float v = o[sub][rr] * ls[rr];
      ctx[(size_t)(r0 + rr) * 4096 + c0 + sub * 16] = f2bf(v);
    }
}

// ---------------------------------------------------------------- launch
extern "C" void kernel_launch(void* const* d_in, const int* in_sizes, int n_in,
                              void* d_out, int out_size, void* d_ws, size_t ws_size,
                              hipStream_t stream) {
  (void)in_sizes; (void)n_in; (void)out_size; (void)ws_size;
  const float* hs     = (const float*)d_in[0];
  const int*   pos    = (const int*)d_in[1];
  const float* cachek = (const float*)d_in[2];
  const float* cachev = (const float*)d_in[3];
  const float* Wq     = (const float*)d_in[4];
  const float* bq     = (const float*)d_in[5];
  const float* Wk     = (const float*)d_in[6];
  const float* bk     = (const float*)d_in[7];
  const float* Wv     = (const float*)d_in[8];
  const float* bv     = (const float*)d_in[9];
  const float* Wo     = (const float*)d_in[10];

  float* out    = (float*)d_out;                     // 2048*4096
  float* keyout = out + (size_t)2048 * 4096;         // 8*4096*128
  float* valout = keyout + (size_t)8 * 4096 * 128;   // 8*4096*128

  char* ws = (char*)d_ws;
  unsigned short* hbf    = (unsigned short*)(ws + 0);
  unsigned short* qbf    = (unsigned short*)(ws + 0);
  char*           kswz   = ws + 16777216;
  char*           vswz   = ws + 25165824;
  unsigned short* wqkvbf = (unsigned short*)(ws + 33554432);
  unsigned short* wobf   = (unsigned short*)(ws + 134217728);
  float*          qkvf   = (float*)(ws + 167772160);
  unsigned short* ctxbf  = (unsigned short*)(ws + 167772160);
  float*          cost   = (float*)(ws + 218103808);
  float*          sint   = (float*)(ws + 218628096);
  float*          biasc  = (float*)(ws + 219152384);

  conv_all<<<2048, 256, 0, stream>>>((const float4*)hs, (const float4*)Wq,
                                     (const float4*)Wk, (const float4*)Wv,
                                     (const float4*)Wo, (const float4*)bq,
                                     (const float4*)bk, (const float4*)bv,
                                     (us4*)hbf, (us4*)wqkvbf, (us4*)wobf,
                                     (float4*)biasc);
  rope_table<<<512, 256, 0, stream>>>(pos, cost, sint);
  gemm8p<3><<<256, 512, 0, stream>>>(hbf, wqkvbf, biasc, qkvf, 2048, 6144, 8192);
  rope_scatter<<<2048, 256, 0, stream>>>(qkvf, cost, sint, cachek, cachev,
                                         keyout, valout, qbf, kswz, vswz);
  attn_fwd<<<512, 512, 0, stream>>>(qbf, kswz, vswz, ctxbf);
  gemm8p<2><<<256, 512, 0, stream>>>(ctxbf, wobf, nullptr, out, 2048, 4096, 4096);
}